// Round 3
// baseline (2761.023 us; speedup 1.0000x reference)
//
#include <hip/hip_runtime.h>
#include <hip/hip_bf16.h>
#include <cstdint>
#include <cstddef>

#define NN 8192
#define DD 256

using bf16 = __hip_bfloat16;
typedef unsigned short ushort_t;

// flag: 1 = inputs/outputs bf16, 0 = fp32
__device__ __forceinline__ float ldin(const void* p, int flag, size_t i) {
  return flag ? __bfloat162float(((const bf16*)p)[i]) : ((const float*)p)[i];
}

// ---------- top-8 insertion helpers ----------
__device__ __forceinline__ void ins8(float v, int jj, float (&lv)[8], int (&li)[8]) {
  if (v <= lv[7]) return;
  int cnt = 0;
#pragma unroll
  for (int s = 0; s < 8; ++s) cnt += (lv[s] >= v) ? 1 : 0;
#pragma unroll
  for (int s = 7; s >= 1; --s) {
    bool sh = (s > cnt);
    lv[s] = sh ? lv[s-1] : lv[s];
    li[s] = sh ? li[s-1] : li[s];
  }
#pragma unroll
  for (int s = 0; s < 8; ++s) if (s == cnt) { lv[s] = v; li[s] = jj; }
}

__device__ __forceinline__ void ins8t(float v, int jj, float (&lv)[8], int (&li)[8]) {
  bool lose = (lv[7] > v) || (lv[7] == v && li[7] < jj);
  if (lose) return;
  int cnt = 0;
#pragma unroll
  for (int s = 0; s < 8; ++s) cnt += ((lv[s] > v) || (lv[s] == v && li[s] < jj)) ? 1 : 0;
#pragma unroll
  for (int s = 7; s >= 1; --s) {
    bool sh = (s > cnt);
    lv[s] = sh ? lv[s-1] : lv[s];
    li[s] = sh ? li[s-1] : li[s];
  }
#pragma unroll
  for (int s = 0; s < 8; ++s) if (s == cnt) { lv[s] = v; li[s] = jj; }
}

// ---------- 0) dtype detection ----------
__global__ void k_detect(const ushort_t* __restrict__ Hu, int* __restrict__ flag) {
  __shared__ int cnt;
  if (threadIdx.x == 0) cnt = 0;
  __syncthreads();
  int sane = 0;
  for (int u = 0; u < 16; ++u) {
    int idx = 2 * (threadIdx.x * 16 + u);
    ushort_t h = Hu[idx];
    int e = (h >> 7) & 0xFF;
    sane += (e >= 113 && e <= 133) ? 1 : 0;
  }
  atomicAdd(&cnt, sane);
  __syncthreads();
  if (threadIdx.x == 0) *flag = (cnt > 2048) ? 1 : 0;
}

// ---------- 1) BN stats, numpy-fp32 mimic: sequential over rows ----------
__global__ void k_stats32(const void* __restrict__ H, const int* __restrict__ pflag,
                          float* __restrict__ mu32, float* __restrict__ rs32) {
  int flag = *pflag;
  int c = blockIdx.x * 64 + threadIdx.x;
  float acc = 0.0f;
#pragma unroll 8
  for (int r = 0; r < NN; ++r)
    acc = __fadd_rn(acc, ldin(H, flag, (size_t)r * DD + c));
  float mu = __fdiv_rn(acc, 8192.0f);
  float vacc = 0.0f;
#pragma unroll 8
  for (int r = 0; r < NN; ++r) {
    float d = __fsub_rn(ldin(H, flag, (size_t)r * DD + c), mu);
    vacc = __fadd_rn(vacc, __fmul_rn(d, d));
  }
  float var = __fdiv_rn(vacc, 8192.0f);
  mu32[c] = mu;
  rs32[c] = __fdiv_rn(1.0f, sqrtf(__fadd_rn(var, 1e-5f)));
}

// ---------- 2) BN apply, numpy op order: ((H-mu)*rs)*gamma + beta ----------
__global__ void k_bn32(const void* __restrict__ H, const int* __restrict__ pflag,
                       const float* __restrict__ mu32, const float* __restrict__ rs32,
                       const void* __restrict__ gamma, const void* __restrict__ beta,
                       float* __restrict__ Hn) {
  int flag = *pflag;
  int i = blockIdx.x, c = threadIdx.x;
  float t = __fsub_rn(ldin(H, flag, (size_t)i * DD + c), mu32[c]);
  t = __fmul_rn(t, rs32[c]);
  t = __fmul_rn(t, ldin(gamma, flag, c));
  t = __fadd_rn(t, ldin(beta, flag, c));
  Hn[(size_t)i * DD + c] = t;
}

// ---------- 3) Hx = Hn @ W_theta + b_theta, k-sequential FMA (sgemm mimic) ----------
__global__ __launch_bounds__(256) void k_hx(const float* __restrict__ Hn,
    const void* __restrict__ Wt, const void* __restrict__ bt, const int* __restrict__ pflag,
    float* __restrict__ Hx) {
  int flag = *pflag;
  __shared__ float sHn[DD];
  int i = blockIdx.x, n = threadIdx.x;
  sHn[n] = Hn[(size_t)i * DD + n];
  __syncthreads();
  float acc = 0.0f;
#pragma unroll 8
  for (int k = 0; k < DD; ++k)
    acc = fmaf(sHn[k], ldin(Wt, flag, (size_t)k * DD + n), acc);
  Hx[(size_t)i * DD + n] = __fadd_rn(acc, ldin(bt, flag, n));
}

// ---------- 4) row normalize, numpy pairwise-sum mimic (n=256 -> two 128-blocks,
//              each 8-accumulator unrolled, fixed combine tree) ----------
__global__ void k_norm32(float* __restrict__ F1) {
  int w = threadIdx.x >> 6, lane = threadIdx.x & 63;
  int row = blockIdx.x * 4 + w;
  float* x = F1 + (size_t)row * DD;
  float part = 0.0f;
  if (lane < 16) {
    int base = (lane >> 3) * 128 + (lane & 7);
    float e0 = x[base];
    part = __fmul_rn(e0, e0);
#pragma unroll
    for (int t = 1; t < 16; ++t) {
      float e = x[base + 8 * t];
      part = __fadd_rn(part, __fmul_rn(e, e));
    }
  }
  float p[16];
#pragma unroll
  for (int s = 0; s < 16; ++s) p[s] = __shfl(part, s, 64);
  float P1 = __fadd_rn(__fadd_rn(__fadd_rn(p[0], p[1]), __fadd_rn(p[2], p[3])),
                       __fadd_rn(__fadd_rn(p[4], p[5]), __fadd_rn(p[6], p[7])));
  float P2 = __fadd_rn(__fadd_rn(__fadd_rn(p[8], p[9]), __fadd_rn(p[10], p[11])),
                       __fadd_rn(__fadd_rn(p[12], p[13]), __fadd_rn(p[14], p[15])));
  float nrm = fmaxf(sqrtf(__fadd_rn(P1, P2)), 1e-12f);
  float v0 = x[lane * 4 + 0], v1 = x[lane * 4 + 1], v2 = x[lane * 4 + 2], v3 = x[lane * 4 + 3];
  x[lane * 4 + 0] = __fdiv_rn(v0, nrm);
  x[lane * 4 + 1] = __fdiv_rn(v1, nrm);
  x[lane * 4 + 2] = __fdiv_rn(v2, nrm);
  x[lane * 4 + 3] = __fdiv_rn(v3, nrm);
}

// ---------- 5) transpose fp32: [N][D] -> [D][N] ----------
__global__ void k_transpose32(const float* __restrict__ F1, float* __restrict__ F1T) {
  __shared__ float tile[64][65];
  int i0 = blockIdx.x * 64;
  int c0 = blockIdx.y * 64;
  int tid = threadIdx.x;
  int r = tid >> 2, cb = (tid & 3) * 16;
#pragma unroll
  for (int u = 0; u < 16; ++u)
    tile[r][cb + u] = F1[(size_t)(i0 + r) * DD + c0 + cb + u];
  __syncthreads();
  int c = tid >> 2, rb = (tid & 3) * 16;
#pragma unroll
  for (int u4 = 0; u4 < 4; ++u4) {
    float4 t;
    t.x = tile[rb + 4*u4 + 0][c];
    t.y = tile[rb + 4*u4 + 1][c];
    t.z = tile[rb + 4*u4 + 2][c];
    t.w = tile[rb + 4*u4 + 3][c];
    *(float4*)&F1T[(size_t)(c0 + c) * NN + i0 + rb + 4*u4] = t;
  }
}

struct Pair { float v; int j; };

// ---------- 6) phase-1 fast fp32 dist GEMM + per-row top-8 candidates ----------
__global__ __launch_bounds__(512) void k_phase1(const float* __restrict__ F1T,
                                                float* __restrict__ candv, int* __restrict__ candi) {
  __shared__ float fat[64 * 132];
  __shared__ float fbt[64 * 68];
  const int eighth = blockIdx.x;
  const int strip  = blockIdx.y;
  const int i0 = strip * 128;
  const int jbase = eighth * 1024;
  const int tid = threadIdx.x;
  const int tx = tid & 15, ty = tid >> 4;

  float lv[4][8]; int li[4][8];
#pragma unroll
  for (int r = 0; r < 4; ++r)
#pragma unroll
    for (int e = 0; e < 8; ++e) { lv[r][e] = -3.0e38f; li[r][e] = 0x7fffffff; }

  const int lk = tid >> 3;
  const int lm = (tid & 7) << 4;
  const int ln = (tid & 7) << 3;

  for (int t = 0; t < 16; ++t) {
    const int j0 = jbase + t * 64;
    float acc[4][4];
#pragma unroll
    for (int r = 0; r < 4; ++r)
#pragma unroll
      for (int c = 0; c < 4; ++c) acc[r][c] = 0.0f;

    for (int kc = 0; kc < DD; kc += 64) {
      __syncthreads();
      const float* gsrcA = F1T + (size_t)(kc + lk) * NN + i0 + lm;
#pragma unroll
      for (int u = 0; u < 4; ++u)
        *(float4*)&fat[lk * 132 + lm + 4*u] = *(const float4*)(gsrcA + 4*u);
      const float* gsrcB = F1T + (size_t)(kc + lk) * NN + j0 + ln;
#pragma unroll
      for (int u = 0; u < 2; ++u)
        *(float4*)&fbt[lk * 68 + ln + 4*u] = *(const float4*)(gsrcB + 4*u);
      __syncthreads();
#pragma unroll 8
      for (int k = 0; k < 64; ++k) {
        float4 a = *(const float4*)&fat[k * 132 + 4 * ty];
        float4 b = *(const float4*)&fbt[k * 68 + 4 * tx];
        acc[0][0] = fmaf(a.x, b.x, acc[0][0]); acc[0][1] = fmaf(a.x, b.y, acc[0][1]);
        acc[0][2] = fmaf(a.x, b.z, acc[0][2]); acc[0][3] = fmaf(a.x, b.w, acc[0][3]);
        acc[1][0] = fmaf(a.y, b.x, acc[1][0]); acc[1][1] = fmaf(a.y, b.y, acc[1][1]);
        acc[1][2] = fmaf(a.y, b.z, acc[1][2]); acc[1][3] = fmaf(a.y, b.w, acc[1][3]);
        acc[2][0] = fmaf(a.z, b.x, acc[2][0]); acc[2][1] = fmaf(a.z, b.y, acc[2][1]);
        acc[2][2] = fmaf(a.z, b.z, acc[2][2]); acc[2][3] = fmaf(a.z, b.w, acc[2][3]);
        acc[3][0] = fmaf(a.w, b.x, acc[3][0]); acc[3][1] = fmaf(a.w, b.y, acc[3][1]);
        acc[3][2] = fmaf(a.w, b.z, acc[3][2]); acc[3][3] = fmaf(a.w, b.w, acc[3][3]);
      }
    }
#pragma unroll
    for (int r = 0; r < 4; ++r)
#pragma unroll
      for (int c = 0; c < 4; ++c)
        ins8(acc[r][c], j0 + 4 * tx + c, lv[r], li[r]);
  }

  Pair* mb = (Pair*)fbt;
  for (int g = 0; g < 8; ++g) {
    __syncthreads();
    if ((ty >> 2) == g) {
      int tyl = ty & 3;
#pragma unroll
      for (int r = 0; r < 4; ++r) {
        int lr = tyl * 4 + r;
#pragma unroll
        for (int e = 0; e < 8; ++e) {
          mb[(lr * 16 + tx) * 8 + e].v = lv[r][e];
          mb[(lr * 16 + tx) * 8 + e].j = li[r][e];
        }
      }
    }
    __syncthreads();
    if (tid < 16) {
      float bv[8]; int bj[8];
#pragma unroll
      for (int e = 0; e < 8; ++e) { bv[e] = -3.0e38f; bj[e] = 0x7fffffff; }
      for (int tt = 0; tt < 16; ++tt)
#pragma unroll
        for (int e = 0; e < 8; ++e) {
          Pair p = mb[(tid * 16 + tt) * 8 + e];
          ins8t(p.v, p.j, bv, bj);
        }
      int row = i0 + g * 16 + tid;
      size_t base = ((size_t)row * 8 + eighth) * 8;
#pragma unroll
      for (int e = 0; e < 8; ++e) { candv[base + e] = bv[e]; candi[base + e] = bj[e]; }
    }
  }
}

// ---------- 7) merge per-eighth lists -> global top-8 ----------
__global__ void k_merge(const float* __restrict__ candv, const int* __restrict__ candi,
                        int* __restrict__ cand8) {
  int row = blockIdx.x * 256 + threadIdx.x;
  float bv[8]; int bj[8];
#pragma unroll
  for (int e = 0; e < 8; ++e) { bv[e] = -3.0e38f; bj[e] = 0x7fffffff; }
  for (int t = 0; t < 64; ++t) {
    float v = candv[(size_t)row * 64 + t];
    int j   = candi[(size_t)row * 64 + t];
    ins8t(v, j, bv, bj);
  }
#pragma unroll
  for (int e = 0; e < 8; ++e) cand8[row * 8 + e] = bj[e];
}

// ---------- 8) re-rank candidates with bitwise fp32-numpy mimic chain ----------
__global__ void k_rerank(const float* __restrict__ F1, const int* __restrict__ cand8,
                         int* __restrict__ top5i, float* __restrict__ top5v,
                         float* __restrict__ dinv) {
  int w = threadIdx.x >> 6, lane = threadIdx.x & 63;
  int row = blockIdx.x * 4 + w;
  int jl = 0x7fffffff;
  float a32 = -1.0f;
  if (lane < 8) {
    jl = cand8[row * 8 + lane];
    const float* xi = F1 + (size_t)row * DD;
    const float* xj = F1 + (size_t)jl * DD;
    float acc = 0.0f;
#pragma unroll 8
    for (int k = 0; k < DD; ++k)
      acc = fmaf(xi[k], xj[k], acc);                 // sgemm: k-sequential FMA
    float d = fminf(fmaxf(acc, -1.0f), 1.0f);        // clip
    float sam = acosf(d);                            // arccos
    float xx = expf(__fmul_rn(-0.2f, sam));          // exp(-0.2*sam)
    float sig = __fdiv_rn(1.0f, __fadd_rn(1.0f, expf(-xx)));  // sigmoid
    a32 = fmaxf(sig, 0.1f);                          // clamp(min=0.1)
  }
  // lane 0 collects and selects top-5 by (value desc, index asc)
  float av[8]; int aj[8];
#pragma unroll
  for (int l = 0; l < 8; ++l) { av[l] = __shfl(a32, l, 64); aj[l] = __shfl(jl, l, 64); }
  if (lane == 0) {
    bool used[8] = {false,false,false,false,false,false,false,false};
    double dsum = 0.0;
#pragma unroll
    for (int k = 0; k < 5; ++k) {
      float bv = -2.0f; int bj = 0x7fffffff; int bs = -1;
#pragma unroll
      for (int s = 0; s < 8; ++s) {
        bool better = (!used[s]) && ((av[s] > bv) || (av[s] == bv && aj[s] < bj));
        bs = better ? s : bs;
        bv = better ? av[s] : bv;
        bj = better ? aj[s] : bj;
      }
#pragma unroll
      for (int s = 0; s < 8; ++s) used[s] = used[s] || (s == bs);
      top5i[row * 5 + k] = bj;
      top5v[row * 5 + k] = bv;
      dsum += (double)bv;
    }
    dinv[row] = (float)(1.0 / sqrt(dsum));
  }
}

// ---------- 9) Z = A_hat @ Hn (5 gathers/row), srow = rowsum(A_hat) ----------
__global__ void k_z(const float* __restrict__ Hn, const int* __restrict__ top5i,
                    const float* __restrict__ top5v, const float* __restrict__ dinv,
                    float* __restrict__ Z, float* __restrict__ srow) {
  __shared__ int sj[5];
  __shared__ float sw[5];
  int i = blockIdx.x, tid = threadIdx.x;
  if (tid < 5) {
    int j = top5i[i * 5 + tid];
    sj[tid] = j;
    sw[tid] = dinv[i] * top5v[i * 5 + tid] * dinv[j];
  }
  __syncthreads();
  double z = 0.0;
#pragma unroll
  for (int k = 0; k < 5; ++k) z += (double)sw[k] * (double)Hn[(size_t)sj[k] * DD + tid];
  Z[(size_t)i * DD + tid] = (float)z;
  if (tid == 0) srow[i] = sw[0] + sw[1] + sw[2] + sw[3] + sw[4];
}

// ---------- 10) out = LeakyReLU(Z @ W_out + srow*b_out) ----------
__global__ __launch_bounds__(256) void k_out2(const float* __restrict__ Z,
    const void* __restrict__ Wo, const void* __restrict__ bo,
    const float* __restrict__ srow, const int* __restrict__ pflag, void* __restrict__ outp) {
  int flag = *pflag;
  __shared__ float As[16][64];
  __shared__ float Bs[16][64];
  const int n0 = blockIdx.x * 64;
  const int i0 = blockIdx.y * 64;
  const int tid = threadIdx.x;
  const int tx = tid & 15, ty = tid >> 4;
  float acc[4][4];
#pragma unroll
  for (int r = 0; r < 4; ++r)
#pragma unroll
    for (int c = 0; c < 4; ++c) acc[r][c] = 0.0f;

  const int lm  = tid >> 2;
  const int lk4 = (tid & 3) * 4;
  const int kb  = tid >> 4;
  const int nb  = (tid & 15) * 4;

  for (int kc = 0; kc < DD; kc += 16) {
    __syncthreads();
    float4 a4 = *(const float4*)&Z[(size_t)(i0 + lm) * DD + kc + lk4];
    As[lk4 + 0][lm] = a4.x; As[lk4 + 1][lm] = a4.y;
    As[lk4 + 2][lm] = a4.z; As[lk4 + 3][lm] = a4.w;
#pragma unroll
    for (int u = 0; u < 4; ++u)
      Bs[kb][nb + u] = ldin(Wo, flag, (size_t)(kc + kb) * DD + n0 + nb + u);
    __syncthreads();
#pragma unroll 4
    for (int k = 0; k < 16; ++k) {
      float a0 = As[k][4*ty+0], a1 = As[k][4*ty+1], a2 = As[k][4*ty+2], a3 = As[k][4*ty+3];
      float b0 = Bs[k][4*tx+0], b1 = Bs[k][4*tx+1], b2 = Bs[k][4*tx+2], b3 = Bs[k][4*tx+3];
      acc[0][0] = fmaf(a0,b0,acc[0][0]); acc[0][1] = fmaf(a0,b1,acc[0][1]); acc[0][2] = fmaf(a0,b2,acc[0][2]); acc[0][3] = fmaf(a0,b3,acc[0][3]);
      acc[1][0] = fmaf(a1,b0,acc[1][0]); acc[1][1] = fmaf(a1,b1,acc[1][1]); acc[1][2] = fmaf(a1,b2,acc[1][2]); acc[1][3] = fmaf(a1,b3,acc[1][3]);
      acc[2][0] = fmaf(a2,b0,acc[2][0]); acc[2][1] = fmaf(a2,b1,acc[2][1]); acc[2][2] = fmaf(a2,b2,acc[2][2]); acc[2][3] = fmaf(a2,b3,acc[2][3]);
      acc[3][0] = fmaf(a3,b0,acc[3][0]); acc[3][1] = fmaf(a3,b1,acc[3][1]); acc[3][2] = fmaf(a3,b2,acc[3][2]); acc[3][3] = fmaf(a3,b3,acc[3][3]);
    }
  }
#pragma unroll
  for (int r = 0; r < 4; ++r) {
    int i = i0 + 4*ty + r;
    float s = srow[i];
#pragma unroll
    for (int c = 0; c < 4; ++c) {
      int col = n0 + 4*tx + c;
      float v = acc[r][c] + s * ldin(bo, flag, col);
      v = (v >= 0.0f) ? v : 0.01f * v;
      if (flag) ((bf16*)outp)[(size_t)i * DD + col] = __float2bfloat16(v);
      else      ((float*)outp)[(size_t)i * DD + col] = v;
    }
  }
}

// ---------- 11) zero-fill A output region ----------
__global__ void k_zeroA(void* __restrict__ d_out, const int* __restrict__ pflag) {
  int flag = *pflag;
  size_t esize = flag ? 2 : 4;
  uint4* base = (uint4*)((char*)d_out + (size_t)NN * DD * esize);
  size_t n16 = ((size_t)NN * NN * esize) >> 4;
  size_t idx = (size_t)blockIdx.x * 256 + threadIdx.x;
  size_t stride = (size_t)gridDim.x * 256;
  uint4 z; z.x = 0; z.y = 0; z.z = 0; z.w = 0;
  for (size_t i = idx; i < n16; i += stride) base[i] = z;
}

// ---------- 12) scatter masked A values ----------
__global__ void k_scatter(void* __restrict__ d_out, const int* __restrict__ pflag,
                          const int* __restrict__ top5i, const float* __restrict__ top5v) {
  int flag = *pflag;
  int t = blockIdx.x * 256 + threadIdx.x;
  if (t >= NN * 5) return;
  int row = t / 5, k = t % 5;
  int col = top5i[row * 5 + k];
  float v = top5v[row * 5 + k];
  size_t off = (size_t)row * NN + col;
  if (flag) ((bf16*)((char*)d_out + (size_t)NN * DD * 2))[off] = __float2bfloat16(v);
  else      ((float*)((char*)d_out + (size_t)NN * DD * 4))[off] = v;
}

extern "C" void kernel_launch(void* const* d_in, const int* in_sizes, int n_in,
                              void* d_out, int out_size, void* d_ws, size_t ws_size,
                              hipStream_t stream) {
  (void)in_sizes; (void)n_in; (void)out_size; (void)ws_size;
  const void* H     = d_in[0];
  const void* gamma = d_in[1];
  const void* beta  = d_in[2];
  const void* Wt    = d_in[3];
  const void* bt    = d_in[4];
  const void* Wo    = d_in[5];
  const void* bo    = d_in[6];

  // scratch zone inside the A-output region (valid in both dtype worlds), freed by k_zeroA
  const size_t MB = 1048576;
  char* zb = (char*)d_out + 8 * MB;
  float* Hn32  = (float*)(zb + 0);              // 8 MiB
  float* F1_32 = (float*)(zb + 8 * MB);         // 8 MiB (Hx -> F1 in place)
  float* F1T   = (float*)(zb + 16 * MB);        // 8 MiB
  float* candv = (float*)(zb + 24 * MB);        // 2 MiB
  int*   candi = (int*)(zb + 26 * MB);          // 2 MiB
  float* Z32   = (float*)(zb + 28 * MB);        // 8 MiB
  float* mu32  = (float*)(zb + 36 * MB);        // 1 KiB
  float* rs32  = (float*)(zb + 36 * MB + 4096); // 1 KiB
  int*   cand8 = (int*)(zb + 36 * MB + 8192);   // 256 KiB
  float* dinv  = (float*)(zb + 36 * MB + 270336);  // 32 KiB
  float* srow  = (float*)(zb + 36 * MB + 303104);  // 32 KiB

  // d_ws: only what must survive k_zeroA
  char* ws = (char*)d_ws;
  int*   flag  = (int*)(ws + 0);
  int*   top5i = (int*)(ws + 256);       // 160 KiB
  float* top5v = (float*)(ws + 164096);  // 160 KiB

  k_detect<<<dim3(1), dim3(256), 0, stream>>>((const ushort_t*)H, flag);
  k_stats32<<<dim3(4), dim3(64), 0, stream>>>(H, flag, mu32, rs32);
  k_bn32<<<dim3(NN), dim3(256), 0, stream>>>(H, flag, mu32, rs32, gamma, beta, Hn32);
  k_hx<<<dim3(NN), dim3(256), 0, stream>>>(Hn32, Wt, bt, flag, F1_32);
  k_norm32<<<dim3(2048), dim3(256), 0, stream>>>(F1_32);
  k_transpose32<<<dim3(128, 4), dim3(256), 0, stream>>>(F1_32, F1T);
  k_phase1<<<dim3(8, 64), dim3(512), 0, stream>>>(F1T, candv, candi);
  k_merge<<<dim3(32), dim3(256), 0, stream>>>(candv, candi, cand8);
  k_rerank<<<dim3(2048), dim3(256), 0, stream>>>(F1_32, cand8, top5i, top5v, dinv);
  k_z<<<dim3(NN), dim3(256), 0, stream>>>(Hn32, top5i, top5v, dinv, Z32, srow);
  k_out2<<<dim3(4, 128), dim3(256), 0, stream>>>(Z32, Wo, bo, srow, flag, d_out);
  k_zeroA<<<dim3(8192), dim3(256), 0, stream>>>(d_out, flag);
  k_scatter<<<dim3(160), dim3(256), 0, stream>>>(d_out, flag, top5i, top5v);
}

// Round 5
// 1633.145 us; speedup vs baseline: 1.6906x; 1.6906x over previous
//
#include <hip/hip_runtime.h>
#include <hip/hip_bf16.h>
#include <cstdint>
#include <cstddef>

#define NN 8192
#define DD 256

using bf16 = __hip_bfloat16;
typedef unsigned short ushort_t;
typedef unsigned int uint32;
typedef short short8 __attribute__((ext_vector_type(8)));
typedef float f32x4 __attribute__((ext_vector_type(4)));

// flag: 1 = inputs/outputs bf16, 0 = fp32
__device__ __forceinline__ float ldin(const void* p, int flag, size_t i) {
  return flag ? __bfloat162float(((const bf16*)p)[i]) : ((const float*)p)[i];
}

// ---------- top-8 insertion helpers ----------
__device__ __forceinline__ void ins8(float v, int jj, float (&lv)[8], int (&li)[8]) {
  if (v <= lv[7]) return;
  int cnt = 0;
#pragma unroll
  for (int s = 0; s < 8; ++s) cnt += (lv[s] >= v) ? 1 : 0;
#pragma unroll
  for (int s = 7; s >= 1; --s) {
    bool sh = (s > cnt);
    lv[s] = sh ? lv[s-1] : lv[s];
    li[s] = sh ? li[s-1] : li[s];
  }
#pragma unroll
  for (int s = 0; s < 8; ++s) if (s == cnt) { lv[s] = v; li[s] = jj; }
}

__device__ __forceinline__ void ins8t(float v, int jj, float (&lv)[8], int (&li)[8]) {
  bool lose = (lv[7] > v) || (lv[7] == v && li[7] < jj);
  if (lose) return;
  int cnt = 0;
#pragma unroll
  for (int s = 0; s < 8; ++s) cnt += ((lv[s] > v) || (lv[s] == v && li[s] < jj)) ? 1 : 0;
#pragma unroll
  for (int s = 7; s >= 1; --s) {
    bool sh = (s > cnt);
    lv[s] = sh ? lv[s-1] : lv[s];
    li[s] = sh ? li[s-1] : li[s];
  }
#pragma unroll
  for (int s = 0; s < 8; ++s) if (s == cnt) { lv[s] = v; li[s] = jj; }
}

// ---------- 0) dtype detection ----------
__global__ void k_detect(const ushort_t* __restrict__ Hu, int* __restrict__ flag) {
  __shared__ int cnt;
  if (threadIdx.x == 0) cnt = 0;
  __syncthreads();
  int sane = 0;
  for (int u = 0; u < 16; ++u) {
    int idx = 2 * (threadIdx.x * 16 + u);
    ushort_t h = Hu[idx];
    int e = (h >> 7) & 0xFF;
    sane += (e >= 113 && e <= 133) ? 1 : 0;
  }
  atomicAdd(&cnt, sane);
  __syncthreads();
  if (threadIdx.x == 0) *flag = (cnt > 2048) ? 1 : 0;
}

// ---------- 1) transpose H -> HT fp32 [DD][NN] (coalesced feed for stats) ----------
__global__ void k_transposeH(const void* __restrict__ H, const int* __restrict__ pflag,
                             float* __restrict__ HT) {
  int flag = *pflag;
  __shared__ float tile[64][65];
  int i0 = blockIdx.x * 64;   // rows
  int c0 = blockIdx.y * 64;   // cols
  int tid = threadIdx.x;
  int r = tid >> 2, cb = (tid & 3) * 16;
#pragma unroll
  for (int u = 0; u < 16; ++u)
    tile[r][cb + u] = ldin(H, flag, (size_t)(i0 + r) * DD + c0 + cb + u);
  __syncthreads();
  int c = tid >> 2, rb = (tid & 3) * 16;
#pragma unroll
  for (int u4 = 0; u4 < 4; ++u4) {
    float4 t;
    t.x = tile[rb + 4*u4 + 0][c];
    t.y = tile[rb + 4*u4 + 1][c];
    t.z = tile[rb + 4*u4 + 2][c];
    t.w = tile[rb + 4*u4 + 3][c];
    *(float4*)&HT[(size_t)(c0 + c) * NN + i0 + rb + 4*u4] = t;
  }
}

// ---------- 2) BN stats: bitwise-identical sequential chains, LDS-staged ----------
__global__ __launch_bounds__(256) void k_statsT(const float* __restrict__ HT,
                                                float* __restrict__ mu32, float* __restrict__ rs32) {
  __shared__ float buf[4][2048];    // 32 KiB
  int c0 = blockIdx.x * 4;
  int w = threadIdx.x >> 6, lane = threadIdx.x & 63;
  int t = threadIdx.x;
  float acc = 0.0f, mu = 0.0f, vacc = 0.0f;
  for (int ch = 0; ch < 4; ++ch) {
    __syncthreads();
#pragma unroll
    for (int it = 0; it < 8; ++it) {
      int idx = it * 256 + lane * 4;
      *(float4*)&buf[w][idx] = *(const float4*)&HT[(size_t)(c0 + w) * NN + ch * 2048 + idx];
    }
    __syncthreads();
    if (t < 4)
      for (int r = 0; r < 2048; ++r) acc = __fadd_rn(acc, buf[t][r]);
  }
  if (t < 4) mu = __fdiv_rn(acc, 8192.0f);
  for (int ch = 0; ch < 4; ++ch) {
    __syncthreads();
#pragma unroll
    for (int it = 0; it < 8; ++it) {
      int idx = it * 256 + lane * 4;
      *(float4*)&buf[w][idx] = *(const float4*)&HT[(size_t)(c0 + w) * NN + ch * 2048 + idx];
    }
    __syncthreads();
    if (t < 4)
      for (int r = 0; r < 2048; ++r) {
        float d = __fsub_rn(buf[t][r], mu);
        vacc = __fadd_rn(vacc, __fmul_rn(d, d));
      }
  }
  if (t < 4) {
    float var = __fdiv_rn(vacc, 8192.0f);
    mu32[c0 + t] = mu;
    rs32[c0 + t] = __fdiv_rn(1.0f, sqrtf(__fadd_rn(var, 1e-5f)));
  }
}

// ---------- 3) BN apply, numpy op order: ((H-mu)*rs)*gamma + beta ----------
__global__ void k_bn32(const void* __restrict__ H, const int* __restrict__ pflag,
                       const float* __restrict__ mu32, const float* __restrict__ rs32,
                       const void* __restrict__ gamma, const void* __restrict__ beta,
                       float* __restrict__ Hn) {
  int flag = *pflag;
  int i = blockIdx.x, c = threadIdx.x;
  float t = __fsub_rn(ldin(H, flag, (size_t)i * DD + c), mu32[c]);
  t = __fmul_rn(t, rs32[c]);
  t = __fmul_rn(t, ldin(gamma, flag, c));
  t = __fadd_rn(t, ldin(beta, flag, c));
  Hn[(size_t)i * DD + c] = t;
}

// ---------- 4) Hx = Hn @ W_theta + b_theta, k-sequential FMA (sgemm mimic) ----------
__global__ __launch_bounds__(256) void k_hx(const float* __restrict__ Hn,
    const void* __restrict__ Wt, const void* __restrict__ bt, const int* __restrict__ pflag,
    float* __restrict__ Hx) {
  int flag = *pflag;
  __shared__ float sHn[DD];
  int i = blockIdx.x, n = threadIdx.x;
  sHn[n] = Hn[(size_t)i * DD + n];
  __syncthreads();
  float acc = 0.0f;
#pragma unroll 8
  for (int k = 0; k < DD; ++k)
    acc = fmaf(sHn[k], ldin(Wt, flag, (size_t)k * DD + n), acc);
  Hx[(size_t)i * DD + n] = __fadd_rn(acc, ldin(bt, flag, n));
}

// ---------- 5) row normalize (numpy pairwise mimic) + emit bf16 hi/lo split ----------
__global__ void k_norm32(float* __restrict__ F1, ushort_t* __restrict__ F1hi,
                         ushort_t* __restrict__ F1lo) {
  int w = threadIdx.x >> 6, lane = threadIdx.x & 63;
  int row = blockIdx.x * 4 + w;
  float* x = F1 + (size_t)row * DD;
  float part = 0.0f;
  if (lane < 16) {
    int base = (lane >> 3) * 128 + (lane & 7);
    float e0 = x[base];
    part = __fmul_rn(e0, e0);
#pragma unroll
    for (int t = 1; t < 16; ++t) {
      float e = x[base + 8 * t];
      part = __fadd_rn(part, __fmul_rn(e, e));
    }
  }
  float p[16];
#pragma unroll
  for (int s = 0; s < 16; ++s) p[s] = __shfl(part, s, 64);
  float P1 = __fadd_rn(__fadd_rn(__fadd_rn(p[0], p[1]), __fadd_rn(p[2], p[3])),
                       __fadd_rn(__fadd_rn(p[4], p[5]), __fadd_rn(p[6], p[7])));
  float P2 = __fadd_rn(__fadd_rn(__fadd_rn(p[8], p[9]), __fadd_rn(p[10], p[11])),
                       __fadd_rn(__fadd_rn(p[12], p[13]), __fadd_rn(p[14], p[15])));
  float nrm = fmaxf(sqrtf(__fadd_rn(P1, P2)), 1e-12f);
#pragma unroll
  for (int u = 0; u < 4; ++u) {
    float xn = __fdiv_rn(x[lane * 4 + u], nrm);
    x[lane * 4 + u] = xn;
    bf16 hi = __float2bfloat16(xn);
    float lo = __fsub_rn(xn, __bfloat162float(hi));
    F1hi[(size_t)row * DD + lane * 4 + u] = *(ushort_t*)&hi;
    bf16 lob = __float2bfloat16(lo);
    F1lo[(size_t)row * DD + lane * 4 + u] = *(ushort_t*)&lob;
  }
}

// ---------- 6) phase-1: split-bf16 MFMA dist GEMM + per-row top-8 candidates ----------
#define PH_AHI 0
#define PH_ALO 1280
#define PH_BHI 2560
#define PH_BLO 7680
__global__ __launch_bounds__(256) void k_phase1_mfma(
    const ushort_t* __restrict__ F1hi, const ushort_t* __restrict__ F1lo,
    float* __restrict__ candv, int* __restrict__ candi) {
  __shared__ uint32 lds[12800];   // 51200 B
  const int quarter = blockIdx.x;       // 0..3
  const int i0 = blockIdx.y * 64;
  const int tid = threadIdx.x;
  const int w = tid >> 6, lane = tid & 63;
  const int quad = lane >> 4, l15 = lane & 15;
  const int arow = tid >> 2, apart = tid & 3;

  float lv[4][8]; int li[4][8];
#pragma unroll
  for (int r = 0; r < 4; ++r)
#pragma unroll
    for (int e = 0; e < 8; ++e) { lv[r][e] = -3.0e38f; li[r][e] = 0x7fffffff; }

  for (int t = 0; t < 8; ++t) {
    const int jb = quarter * 2048 + t * 256;
    f32x4 acc[16];
#pragma unroll
    for (int ct = 0; ct < 16; ++ct) acc[ct] = (f32x4)0.0f;

    for (int kc = 0; kc < DD; kc += 32) {
      __syncthreads();
      *(uint4*)&lds[PH_AHI + arow * 20 + apart * 4] =
          *(const uint4*)(F1hi + (size_t)(i0 + arow) * DD + kc + apart * 8);
      *(uint4*)&lds[PH_ALO + arow * 20 + apart * 4] =
          *(const uint4*)(F1lo + (size_t)(i0 + arow) * DD + kc + apart * 8);
#pragma unroll
      for (int it = 0; it < 4; ++it) {
        int jrow = arow + it * 64;
        *(uint4*)&lds[PH_BHI + jrow * 20 + apart * 4] =
            *(const uint4*)(F1hi + (size_t)(jb + jrow) * DD + kc + apart * 8);
        *(uint4*)&lds[PH_BLO + jrow * 20 + apart * 4] =
            *(const uint4*)(F1lo + (size_t)(jb + jrow) * DD + kc + apart * 8);
      }
      __syncthreads();
      short8 a_hi = *(const short8*)&lds[PH_AHI + (w * 16 + l15) * 20 + quad * 4];
      short8 a_lo = *(const short8*)&lds[PH_ALO + (w * 16 + l15) * 20 + quad * 4];
#pragma unroll
      for (int ct = 0; ct < 16; ++ct) {
        short8 b_hi = *(const short8*)&lds[PH_BHI + (ct * 16 + l15) * 20 + quad * 4];
        short8 b_lo = *(const short8*)&lds[PH_BLO + (ct * 16 + l15) * 20 + quad * 4];
        acc[ct] = __builtin_amdgcn_mfma_f32_16x16x32_bf16(a_hi, b_hi, acc[ct], 0, 0, 0);
        acc[ct] = __builtin_amdgcn_mfma_f32_16x16x32_bf16(a_hi, b_lo, acc[ct], 0, 0, 0);
        acc[ct] = __builtin_amdgcn_mfma_f32_16x16x32_bf16(a_lo, b_hi, acc[ct], 0, 0, 0);
      }
    }
#pragma unroll
    for (int ct = 0; ct < 16; ++ct) {
      int j = jb + ct * 16 + l15;
#pragma unroll
      for (int r = 0; r < 4; ++r)
        ins8(acc[ct][r], j, lv[r], li[r]);
    }
  }
#pragma unroll
  for (int m = 1; m <= 8; m <<= 1) {
#pragma unroll
    for (int r = 0; r < 4; ++r) {
      float tv[8]; int tj[8];
#pragma unroll
      for (int e = 0; e < 8; ++e) {
        tv[e] = __shfl_xor(lv[r][e], m, 64);
        tj[e] = __shfl_xor(li[r][e], m, 64);
      }
#pragma unroll
      for (int e = 0; e < 8; ++e) ins8t(tv[e], tj[e], lv[r], li[r]);
    }
  }
  if (l15 == 0) {
#pragma unroll
    for (int r = 0; r < 4; ++r) {
      int row = i0 + w * 16 + quad * 4 + r;
      size_t base = ((size_t)row * 4 + quarter) * 8;
#pragma unroll
      for (int e = 0; e < 8; ++e) { candv[base + e] = lv[r][e]; candi[base + e] = li[r][e]; }
    }
  }
}

// ---------- 7) merge 4 per-quarter lists -> global top-8 per row ----------
__global__ void k_merge(const float* __restrict__ candv, const int* __restrict__ candi,
                        int* __restrict__ cand8) {
  int row = blockIdx.x * 256 + threadIdx.x;
  float bv[8]; int bj[8];
#pragma unroll
  for (int e = 0; e < 8; ++e) { bv[e] = -3.0e38f; bj[e] = 0x7fffffff; }
  for (int t = 0; t < 32; ++t) {
    float v = candv[(size_t)row * 32 + t];
    int j   = candi[(size_t)row * 32 + t];
    ins8t(v, j, bv, bj);
  }
#pragma unroll
  for (int e = 0; e < 8; ++e) cand8[row * 8 + e] = bj[e];
}

// ---------- 8) re-rank candidates with bitwise fp32-numpy mimic chain ----------
__global__ void k_rerank(const float* __restrict__ F1, const int* __restrict__ cand8,
                         int* __restrict__ top5i, float* __restrict__ top5v,
                         float* __restrict__ dinv) {
  int w = threadIdx.x >> 6, lane = threadIdx.x & 63;
  int row = blockIdx.x * 4 + w;
  int jl = 0x7fffffff;
  float a32 = -1.0f;
  if (lane < 8) {
    jl = cand8[row * 8 + lane];
    const float* xi = F1 + (size_t)row * DD;
    const float* xj = F1 + (size_t)jl * DD;
    float acc = 0.0f;
#pragma unroll 8
    for (int k = 0; k < DD; ++k)
      acc = fmaf(xi[k], xj[k], acc);
    float d = fminf(fmaxf(acc, -1.0f), 1.0f);
    float sam = acosf(d);
    float xx = expf(__fmul_rn(-0.2f, sam));
    float sig = __fdiv_rn(1.0f, __fadd_rn(1.0f, expf(-xx)));
    a32 = fmaxf(sig, 0.1f);
  }
  float av[8]; int aj[8];
#pragma unroll
  for (int l = 0; l < 8; ++l) { av[l] = __shfl(a32, l, 64); aj[l] = __shfl(jl, l, 64); }
  if (lane == 0) {
    bool used[8] = {false,false,false,false,false,false,false,false};
    double dsum = 0.0;
#pragma unroll
    for (int k = 0; k < 5; ++k) {
      float bv = -2.0f; int bj = 0x7fffffff; int bs = -1;
#pragma unroll
      for (int s = 0; s < 8; ++s) {
        bool better = (!used[s]) && ((av[s] > bv) || (av[s] == bv && aj[s] < bj));
        bs = better ? s : bs;
        bv = better ? av[s] : bv;
        bj = better ? aj[s] : bj;
      }
#pragma unroll
      for (int s = 0; s < 8; ++s) used[s] = used[s] || (s == bs);
      top5i[row * 5 + k] = bj;
      top5v[row * 5 + k] = bv;
      dsum += (double)bv;
    }
    dinv[row] = (float)(1.0 / sqrt(dsum));
  }
}

// ---------- 9) Z = A_hat @ Hn (5 gathers/row), srow = rowsum(A_hat) ----------
__global__ void k_z(const float* __restrict__ Hn, const int* __restrict__ top5i,
                    const float* __restrict__ top5v, const float* __restrict__ dinv,
                    float* __restrict__ Z, float* __restrict__ srow) {
  __shared__ int sj[5];
  __shared__ float sw[5];
  int i = blockIdx.x, tid = threadIdx.x;
  if (tid < 5) {
    int j = top5i[i * 5 + tid];
    sj[tid] = j;
    sw[tid] = dinv[i] * top5v[i * 5 + tid] * dinv[j];
  }
  __syncthreads();
  double z = 0.0;
#pragma unroll
  for (int k = 0; k < 5; ++k) z += (double)sw[k] * (double)Hn[(size_t)sj[k] * DD + tid];
  Z[(size_t)i * DD + tid] = (float)z;
  if (tid == 0) srow[i] = sw[0] + sw[1] + sw[2] + sw[3] + sw[4];
}

// ---------- 10) out = LeakyReLU(Z @ W_out + srow*b_out) ----------
__global__ __launch_bounds__(256) void k_out2(const float* __restrict__ Z,
    const void* __restrict__ Wo, const void* __restrict__ bo,
    const float* __restrict__ srow, const int* __restrict__ pflag, void* __restrict__ outp) {
  int flag = *pflag;
  __shared__ float As[16][64];
  __shared__ float Bs[16][64];
  const int n0 = blockIdx.x * 64;
  const int i0 = blockIdx.y * 64;
  const int tid = threadIdx.x;
  const int tx = tid & 15, ty = tid >> 4;
  float acc[4][4];
#pragma unroll
  for (int r = 0; r < 4; ++r)
#pragma unroll
    for (int c = 0; c < 4; ++c) acc[r][c] = 0.0f;

  const int lm  = tid >> 2;
  const int lk4 = (tid & 3) * 4;
  const int kb  = tid >> 4;
  const int nb  = (tid & 15) * 4;

  for (int kc = 0; kc < DD; kc += 16) {
    __syncthreads();
    float4 a4 = *(const float4*)&Z[(size_t)(i0 + lm) * DD + kc + lk4];
    As[lk4 + 0][lm] = a4.x; As[lk4 + 1][lm] = a4.y;
    As[lk4 + 2][lm] = a4.z; As[lk4 + 3][lm] = a4.w;
#pragma unroll
    for (int u = 0; u < 4; ++u)
      Bs[kb][nb + u] = ldin(Wo, flag, (size_t)(kc + kb) * DD + n0 + nb + u);
    __syncthreads();
#pragma unroll 4
    for (int k = 0; k < 16; ++k) {
      float a0 = As[k][4*ty+0], a1 = As[k][4*ty+1], a2 = As[k][4*ty+2], a3 = As[k][4*ty+3];
      float b0 = Bs[k][4*tx+0], b1 = Bs[k][4*tx+1], b2 = Bs[k][4*tx+2], b3 = Bs[k][4*tx+3];
      acc[0][0] = fmaf(a0,b0,acc[0][0]); acc[0][1] = fmaf(a0,b1,acc[0][1]); acc[0][2] = fmaf(a0,b2,acc[0][2]); acc[0][3] = fmaf(a0,b3,acc[0][3]);
      acc[1][0] = fmaf(a1,b0,acc[1][0]); acc[1][1] = fmaf(a1,b1,acc[1][1]); acc[1][2] = fmaf(a1,b2,acc[1][2]); acc[1][3] = fmaf(a1,b3,acc[1][3]);
      acc[2][0] = fmaf(a2,b0,acc[2][0]); acc[2][1] = fmaf(a2,b1,acc[2][1]); acc[2][2] = fmaf(a2,b2,acc[2][2]); acc[2][3] = fmaf(a2,b3,acc[2][3]);
      acc[3][0] = fmaf(a3,b0,acc[3][0]); acc[3][1] = fmaf(a3,b1,acc[3][1]); acc[3][2] = fmaf(a3,b2,acc[3][2]); acc[3][3] = fmaf(a3,b3,acc[3][3]);
    }
  }
#pragma unroll
  for (int r = 0; r < 4; ++r) {
    int i = i0 + 4*ty + r;
    float s = srow[i];
#pragma unroll
    for (int c = 0; c < 4; ++c) {
      int col = n0 + 4*tx + c;
      float v = acc[r][c] + s * ldin(bo, flag, col);
      v = (v >= 0.0f) ? v : 0.01f * v;
      if (flag) ((bf16*)outp)[(size_t)i * DD + col] = __float2bfloat16(v);
      else      ((float*)outp)[(size_t)i * DD + col] = v;
    }
  }
}

// ---------- 11) zero-fill A output region ----------
__global__ void k_zeroA(void* __restrict__ d_out, const int* __restrict__ pflag) {
  int flag = *pflag;
  size_t esize = flag ? 2 : 4;
  uint4* base = (uint4*)((char*)d_out + (size_t)NN * DD * esize);
  size_t n16 = ((size_t)NN * NN * esize) >> 4;
  size_t idx = (size_t)blockIdx.x * 256 + threadIdx.x;
  size_t stride = (size_t)gridDim.x * 256;
  uint4 z; z.x = 0; z.y = 0; z.z = 0; z.w = 0;
  for (size_t i = idx; i < n16; i += stride) base[i] = z;
}

// ---------- 12) scatter masked A values ----------
__global__ void k_scatter(void* __restrict__ d_out, const int* __restrict__ pflag,
                          const int* __restrict__ top5i, const float* __restrict__ top5v) {
  int flag = *pflag;
  int t = blockIdx.x * 256 + threadIdx.x;
  if (t >= NN * 5) return;
  int row = t / 5, k = t % 5;
  int col = top5i[row * 5 + k];
  float v = top5v[row * 5 + k];
  size_t off = (size_t)row * NN + col;
  if (flag) ((bf16*)((char*)d_out + (size_t)NN * DD * 2))[off] = __float2bfloat16(v);
  else      ((float*)((char*)d_out + (size_t)NN * DD * 4))[off] = v;
}

extern "C" void kernel_launch(void* const* d_in, const int* in_sizes, int n_in,
                              void* d_out, int out_size, void* d_ws, size_t ws_size,
                              hipStream_t stream) {
  (void)in_sizes; (void)n_in; (void)out_size; (void)ws_size;
  const void* H     = d_in[0];
  const void* gamma = d_in[1];
  const void* beta  = d_in[2];
  const void* Wt    = d_in[3];
  const void* bt    = d_in[4];
  const void* Wo    = d_in[5];
  const void* bo    = d_in[6];

  // scratch zone inside the A-output region (valid in both dtype worlds), freed by k_zeroA
  const size_t MB = 1048576;
  char* zb = (char*)d_out + 8 * MB;
  float*    Hn32  = (float*)(zb + 0);              // 8 MiB
  float*    F1_32 = (float*)(zb + 8 * MB);         // 8 MiB (Hx -> F1 in place)
  ushort_t* F1hi  = (ushort_t*)(zb + 16 * MB);     // 4 MiB
  ushort_t* F1lo  = (ushort_t*)(zb + 20 * MB);     // 4 MiB
  float*    candv = (float*)(zb + 24 * MB);        // 1 MiB
  int*      candi = (int*)(zb + 25 * MB);          // 1 MiB
  float*    Z32   = (float*)(zb + 28 * MB);        // 8 MiB
  float*    HT    = (float*)(zb + 36 * MB);        // 8 MiB [DD][NN]
  float*    mu32  = (float*)(zb + 44 * MB);        // 1 KiB
  float*    rs32  = (float*)(zb + 44 * MB + 4096); // 1 KiB
  int*      cand8 = (int*)(zb + 44 * MB + 8192);   // 256 KiB
  float*    dinv  = (float*)(zb + 44 * MB + 270336);  // 32 KiB
  float*    srow  = (float*)(zb + 44 * MB + 303104);  // 32 KiB

  // d_ws: only what must survive k_zeroA
  char* ws = (char*)d_ws;
  int*   flag  = (int*)(ws + 0);
  int*   top5i = (int*)(ws + 256);       // 160 KiB
  float* top5v = (float*)(ws + 164096);  // 160 KiB

  k_detect<<<dim3(1), dim3(256), 0, stream>>>((const ushort_t*)H, flag);
  k_transposeH<<<dim3(128, 4), dim3(256), 0, stream>>>(H, flag, HT);
  k_statsT<<<dim3(64), dim3(256), 0, stream>>>(HT, mu32, rs32);
  k_bn32<<<dim3(NN), dim3(256), 0, stream>>>(H, flag, mu32, rs32, gamma, beta, Hn32);
  k_hx<<<dim3(NN), dim3(256), 0, stream>>>(Hn32, Wt, bt, flag, F1_32);
  k_norm32<<<dim3(2048), dim3(256), 0, stream>>>(F1_32, F1hi, F1lo);
  k_phase1_mfma<<<dim3(4, 128), dim3(256), 0, stream>>>(F1hi, F1lo, candv, candi);
  k_merge<<<dim3(32), dim3(256), 0, stream>>>(candv, candi, cand8);
  k_rerank<<<dim3(2048), dim3(256), 0, stream>>>(F1_32, cand8, top5i, top5v, dinv);
  k_z<<<dim3(NN), dim3(256), 0, stream>>>(Hn32, top5i, top5v, dinv, Z32, srow);
  k_out2<<<dim3(4, 128), dim3(256), 0, stream>>>(Z32, Wo, bo, srow, flag, d_out);
  k_zeroA<<<dim3(8192), dim3(256), 0, stream>>>(d_out, flag);
  k_scatter<<<dim3(160), dim3(256), 0, stream>>>(d_out, flag, top5i, top5v);
}

// Round 6
// 1339.685 us; speedup vs baseline: 2.0609x; 1.2191x over previous
//
#include <hip/hip_runtime.h>
#include <hip/hip_bf16.h>
#include <cstdint>
#include <cstddef>

#define NN 8192
#define DD 256

using bf16 = __hip_bfloat16;
typedef unsigned short ushort_t;
typedef unsigned int uint32;
typedef short short8 __attribute__((ext_vector_type(8)));
typedef float f32x4 __attribute__((ext_vector_type(4)));

// flag: 1 = inputs/outputs bf16, 0 = fp32
__device__ __forceinline__ float ldin(const void* p, int flag, size_t i) {
  return flag ? __bfloat162float(((const bf16*)p)[i]) : ((const float*)p)[i];
}

// ---------- top-8 insertion helpers ----------
__device__ __forceinline__ void ins8(float v, int jj, float (&lv)[8], int (&li)[8]) {
  if (v <= lv[7]) return;
  int cnt = 0;
#pragma unroll
  for (int s = 0; s < 8; ++s) cnt += (lv[s] >= v) ? 1 : 0;
#pragma unroll
  for (int s = 7; s >= 1; --s) {
    bool sh = (s > cnt);
    lv[s] = sh ? lv[s-1] : lv[s];
    li[s] = sh ? li[s-1] : li[s];
  }
#pragma unroll
  for (int s = 0; s < 8; ++s) if (s == cnt) { lv[s] = v; li[s] = jj; }
}

__device__ __forceinline__ void ins8t(float v, int jj, float (&lv)[8], int (&li)[8]) {
  bool lose = (lv[7] > v) || (lv[7] == v && li[7] < jj);
  if (lose) return;
  int cnt = 0;
#pragma unroll
  for (int s = 0; s < 8; ++s) cnt += ((lv[s] > v) || (lv[s] == v && li[s] < jj)) ? 1 : 0;
#pragma unroll
  for (int s = 7; s >= 1; --s) {
    bool sh = (s > cnt);
    lv[s] = sh ? lv[s-1] : lv[s];
    li[s] = sh ? li[s-1] : li[s];
  }
#pragma unroll
  for (int s = 0; s < 8; ++s) if (s == cnt) { lv[s] = v; li[s] = jj; }
}

// ---------- 0) dtype detection ----------
__global__ void k_detect(const ushort_t* __restrict__ Hu, int* __restrict__ flag) {
  __shared__ int cnt;
  if (threadIdx.x == 0) cnt = 0;
  __syncthreads();
  int sane = 0;
  for (int u = 0; u < 16; ++u) {
    int idx = 2 * (threadIdx.x * 16 + u);
    ushort_t h = Hu[idx];
    int e = (h >> 7) & 0xFF;
    sane += (e >= 113 && e <= 133) ? 1 : 0;
  }
  atomicAdd(&cnt, sane);
  __syncthreads();
  if (threadIdx.x == 0) *flag = (cnt > 2048) ? 1 : 0;
}

// ---------- 1) transpose H -> HT fp32 [DD][NN] ----------
__global__ void k_transposeH(const void* __restrict__ H, const int* __restrict__ pflag,
                             float* __restrict__ HT) {
  int flag = *pflag;
  __shared__ float tile[64][65];
  int i0 = blockIdx.x * 64;
  int c0 = blockIdx.y * 64;
  int tid = threadIdx.x;
  int r = tid >> 2, cb = (tid & 3) * 16;
#pragma unroll
  for (int u = 0; u < 16; ++u)
    tile[r][cb + u] = ldin(H, flag, (size_t)(i0 + r) * DD + c0 + cb + u);
  __syncthreads();
  int c = tid >> 2, rb = (tid & 3) * 16;
#pragma unroll
  for (int u4 = 0; u4 < 4; ++u4) {
    float4 t;
    t.x = tile[rb + 4*u4 + 0][c];
    t.y = tile[rb + 4*u4 + 1][c];
    t.z = tile[rb + 4*u4 + 2][c];
    t.w = tile[rb + 4*u4 + 3][c];
    *(float4*)&HT[(size_t)(c0 + c) * NN + i0 + rb + 4*u4] = t;
  }
}

// ---------- 2) BN stats: bitwise-identical sequential chains, LDS-staged ----------
__global__ __launch_bounds__(256) void k_statsT(const float* __restrict__ HT,
                                                float* __restrict__ mu32, float* __restrict__ rs32) {
  __shared__ float buf[4][2048];
  int c0 = blockIdx.x * 4;
  int w = threadIdx.x >> 6, lane = threadIdx.x & 63;
  int t = threadIdx.x;
  float acc = 0.0f, mu = 0.0f, vacc = 0.0f;
  for (int ch = 0; ch < 4; ++ch) {
    __syncthreads();
#pragma unroll
    for (int it = 0; it < 8; ++it) {
      int idx = it * 256 + lane * 4;
      *(float4*)&buf[w][idx] = *(const float4*)&HT[(size_t)(c0 + w) * NN + ch * 2048 + idx];
    }
    __syncthreads();
    if (t < 4)
      for (int r = 0; r < 2048; ++r) acc = __fadd_rn(acc, buf[t][r]);
  }
  if (t < 4) mu = __fdiv_rn(acc, 8192.0f);
  for (int ch = 0; ch < 4; ++ch) {
    __syncthreads();
#pragma unroll
    for (int it = 0; it < 8; ++it) {
      int idx = it * 256 + lane * 4;
      *(float4*)&buf[w][idx] = *(const float4*)&HT[(size_t)(c0 + w) * NN + ch * 2048 + idx];
    }
    __syncthreads();
    if (t < 4)
      for (int r = 0; r < 2048; ++r) {
        float d = __fsub_rn(buf[t][r], mu);
        vacc = __fadd_rn(vacc, __fmul_rn(d, d));
      }
  }
  if (t < 4) {
    float var = __fdiv_rn(vacc, 8192.0f);
    mu32[c0 + t] = mu;
    rs32[c0 + t] = __fdiv_rn(1.0f, sqrtf(__fadd_rn(var, 1e-5f)));
  }
}

// ---------- 3) BN apply ----------
__global__ void k_bn32(const void* __restrict__ H, const int* __restrict__ pflag,
                       const float* __restrict__ mu32, const float* __restrict__ rs32,
                       const void* __restrict__ gamma, const void* __restrict__ beta,
                       float* __restrict__ Hn) {
  int flag = *pflag;
  int i = blockIdx.x, c = threadIdx.x;
  float t = __fsub_rn(ldin(H, flag, (size_t)i * DD + c), mu32[c]);
  t = __fmul_rn(t, rs32[c]);
  t = __fmul_rn(t, ldin(gamma, flag, c));
  t = __fadd_rn(t, ldin(beta, flag, c));
  Hn[(size_t)i * DD + c] = t;
}

// ---------- 4) Hx = Hn @ W_theta + b_theta (sgemm mimic) ----------
__global__ __launch_bounds__(256) void k_hx(const float* __restrict__ Hn,
    const void* __restrict__ Wt, const void* __restrict__ bt, const int* __restrict__ pflag,
    float* __restrict__ Hx) {
  int flag = *pflag;
  __shared__ float sHn[DD];
  int i = blockIdx.x, n = threadIdx.x;
  sHn[n] = Hn[(size_t)i * DD + n];
  __syncthreads();
  float acc = 0.0f;
#pragma unroll 8
  for (int k = 0; k < DD; ++k)
    acc = fmaf(sHn[k], ldin(Wt, flag, (size_t)k * DD + n), acc);
  Hx[(size_t)i * DD + n] = __fadd_rn(acc, ldin(bt, flag, n));
}

// ---------- 5) row normalize (numpy pairwise mimic) + emit bf16 hi/lo split ----------
__global__ void k_norm32(float* __restrict__ F1, ushort_t* __restrict__ F1hi,
                         ushort_t* __restrict__ F1lo) {
  int w = threadIdx.x >> 6, lane = threadIdx.x & 63;
  int row = blockIdx.x * 4 + w;
  float* x = F1 + (size_t)row * DD;
  float part = 0.0f;
  if (lane < 16) {
    int base = (lane >> 3) * 128 + (lane & 7);
    float e0 = x[base];
    part = __fmul_rn(e0, e0);
#pragma unroll
    for (int t = 1; t < 16; ++t) {
      float e = x[base + 8 * t];
      part = __fadd_rn(part, __fmul_rn(e, e));
    }
  }
  float p[16];
#pragma unroll
  for (int s = 0; s < 16; ++s) p[s] = __shfl(part, s, 64);
  float P1 = __fadd_rn(__fadd_rn(__fadd_rn(p[0], p[1]), __fadd_rn(p[2], p[3])),
                       __fadd_rn(__fadd_rn(p[4], p[5]), __fadd_rn(p[6], p[7])));
  float P2 = __fadd_rn(__fadd_rn(__fadd_rn(p[8], p[9]), __fadd_rn(p[10], p[11])),
                       __fadd_rn(__fadd_rn(p[12], p[13]), __fadd_rn(p[14], p[15])));
  float nrm = fmaxf(sqrtf(__fadd_rn(P1, P2)), 1e-12f);
#pragma unroll
  for (int u = 0; u < 4; ++u) {
    float xn = __fdiv_rn(x[lane * 4 + u], nrm);
    x[lane * 4 + u] = xn;
    bf16 hi = __float2bfloat16(xn);
    float lo = __fsub_rn(xn, __bfloat162float(hi));
    F1hi[(size_t)row * DD + lane * 4 + u] = *(ushort_t*)&hi;
    bf16 lob = __float2bfloat16(lo);
    F1lo[(size_t)row * DD + lane * 4 + u] = *(ushort_t*)&lob;
  }
}

// ---------- 6) S-chunk GEMM: S[:, jc*2048 .. +2048) = hh + hl + lh ----------
// 128x128 tile, BK=64, 4 waves (2x2 of 64x64). Effective K=768 via 12 chunks:
// 0-3: A=hi,B=hi; 4-7: A=hi,B=lo; 8-11: A=lo,B=hi. XOR-swizzled LDS (16B chunk
// cc^(row&7)) -> conflict-free ds_write_b128 staging and ds_read_b128 frags.
__global__ __launch_bounds__(256) void k_gemm_s(
    const ushort_t* __restrict__ F1hi, const ushort_t* __restrict__ F1lo,
    int jc, float* __restrict__ S) {
  __shared__ __align__(16) ushort_t Abuf[8192];   // [128][64]
  __shared__ __align__(16) ushort_t Bbuf[8192];
  const int tid = threadIdx.x;
  const int w = tid >> 6, lane = tid & 63;
  const int quad = lane >> 4, l15 = lane & 15;
  const int wi = w >> 1, wj = w & 1;
  const int i0 = blockIdx.y * 128;
  const int j0loc = blockIdx.x * 128;        // within chunk
  const int j0 = jc * 2048 + j0loc;          // global column

  f32x4 acc[4][4];
#pragma unroll
  for (int fr = 0; fr < 4; ++fr)
#pragma unroll
    for (int fc = 0; fc < 4; ++fc) acc[fr][fc] = (f32x4)0.0f;

  // staging decode (4 chunks each for A and B per thread)
  int srow[4], scc[4];
#pragma unroll
  for (int it = 0; it < 4; ++it) {
    int c = it * 256 + tid;
    srow[it] = c >> 3;
    scc[it] = (c & 7) ^ (srow[it] & 7);
  }

  for (int chunk = 0; chunk < 12; ++chunk) {
    const int seg = chunk >> 2;
    const int kofs = (chunk & 3) * 64;
    const ushort_t* Ap = (seg < 2) ? F1hi : F1lo;
    const ushort_t* Bp = (seg == 1) ? F1lo : F1hi;
    // global loads (overlap previous compute)
    uint4 va[4], vb[4];
#pragma unroll
    for (int it = 0; it < 4; ++it)
      va[it] = *(const uint4*)(Ap + (size_t)(i0 + srow[it]) * DD + kofs + scc[it] * 8);
#pragma unroll
    for (int it = 0; it < 4; ++it)
      vb[it] = *(const uint4*)(Bp + (size_t)(j0 + srow[it]) * DD + kofs + scc[it] * 8);
    __syncthreads();
#pragma unroll
    for (int it = 0; it < 4; ++it) {
      int c = it * 256 + tid;
      *(uint4*)&Abuf[c * 8] = va[it];
      *(uint4*)&Bbuf[c * 8] = vb[it];
    }
    __syncthreads();
#pragma unroll
    for (int ks = 0; ks < 2; ++ks) {
      short8 af[4], bf[4];
#pragma unroll
      for (int fr = 0; fr < 4; ++fr) {
        int row = wi * 64 + fr * 16 + l15;
        int cch = (ks * 4 + quad) ^ (row & 7);
        af[fr] = *(const short8*)&Abuf[(row * 8 + cch) * 8];
      }
#pragma unroll
      for (int fc = 0; fc < 4; ++fc) {
        int row = wj * 64 + fc * 16 + l15;
        int cch = (ks * 4 + quad) ^ (row & 7);
        bf[fc] = *(const short8*)&Bbuf[(row * 8 + cch) * 8];
      }
#pragma unroll
      for (int fr = 0; fr < 4; ++fr)
#pragma unroll
        for (int fc = 0; fc < 4; ++fc)
          acc[fr][fc] = __builtin_amdgcn_mfma_f32_16x16x32_bf16(af[fr], bf[fc], acc[fr][fc], 0, 0, 0);
    }
  }
  // epilogue: C layout col=l15, row=quad*4+reg
#pragma unroll
  for (int fr = 0; fr < 4; ++fr) {
#pragma unroll
    for (int reg = 0; reg < 4; ++reg) {
      int row = i0 + wi * 64 + fr * 16 + quad * 4 + reg;
#pragma unroll
      for (int fc = 0; fc < 4; ++fc) {
        int coll = j0loc + wj * 64 + fc * 16 + l15;
        S[(size_t)row * 2048 + coll] = acc[fr][fc][reg];
      }
    }
  }
}

// ---------- 7) per-chunk top-8 scan of S ----------
__global__ __launch_bounds__(256) void k_scan(const float* __restrict__ S, int jc,
                                              float* __restrict__ candv, int* __restrict__ candi) {
  int w = threadIdx.x >> 6, lane = threadIdx.x & 63;
  int row = blockIdx.x * 4 + w;
  const int jbase = jc * 2048;
  float lv[8]; int li[8];
#pragma unroll
  for (int e = 0; e < 8; ++e) { lv[e] = -3.0e38f; li[e] = 0x7fffffff; }
  const float* p = S + (size_t)row * 2048;
#pragma unroll
  for (int it = 0; it < 8; ++it) {
    int col = it * 256 + lane * 4;
    float4 v = *(const float4*)&p[col];
    ins8(v.x, jbase + col + 0, lv, li);
    ins8(v.y, jbase + col + 1, lv, li);
    ins8(v.z, jbase + col + 2, lv, li);
    ins8(v.w, jbase + col + 3, lv, li);
  }
#pragma unroll
  for (int m = 1; m <= 32; m <<= 1) {
    float tv[8]; int tj[8];
#pragma unroll
    for (int e = 0; e < 8; ++e) {
      tv[e] = __shfl_xor(lv[e], m, 64);
      tj[e] = __shfl_xor(li[e], m, 64);
    }
#pragma unroll
    for (int e = 0; e < 8; ++e) ins8t(tv[e], tj[e], lv, li);
  }
  if (lane == 0) {
    size_t base = ((size_t)row * 4 + jc) * 8;
#pragma unroll
    for (int e = 0; e < 8; ++e) { candv[base + e] = lv[e]; candi[base + e] = li[e]; }
  }
}

// ---------- 8) merge 4 per-chunk lists -> global top-8 per row ----------
__global__ void k_merge(const float* __restrict__ candv, const int* __restrict__ candi,
                        int* __restrict__ cand8) {
  int row = blockIdx.x * 256 + threadIdx.x;
  float bv[8]; int bj[8];
#pragma unroll
  for (int e = 0; e < 8; ++e) { bv[e] = -3.0e38f; bj[e] = 0x7fffffff; }
  for (int t = 0; t < 32; ++t) {
    float v = candv[(size_t)row * 32 + t];
    int j   = candi[(size_t)row * 32 + t];
    ins8t(v, j, bv, bj);
  }
#pragma unroll
  for (int e = 0; e < 8; ++e) cand8[row * 8 + e] = bj[e];
}

// ---------- 9) re-rank candidates with bitwise fp32-numpy mimic chain ----------
__global__ void k_rerank(const float* __restrict__ F1, const int* __restrict__ cand8,
                         int* __restrict__ top5i, float* __restrict__ top5v,
                         float* __restrict__ dinv) {
  int w = threadIdx.x >> 6, lane = threadIdx.x & 63;
  int row = blockIdx.x * 4 + w;
  int jl = 0x7fffffff;
  float a32 = -1.0f;
  if (lane < 8) {
    jl = cand8[row * 8 + lane];
    const float* xi = F1 + (size_t)row * DD;
    const float* xj = F1 + (size_t)jl * DD;
    float acc = 0.0f;
#pragma unroll 8
    for (int k = 0; k < DD; ++k)
      acc = fmaf(xi[k], xj[k], acc);
    float d = fminf(fmaxf(acc, -1.0f), 1.0f);
    float sam = acosf(d);
    float xx = expf(__fmul_rn(-0.2f, sam));
    float sig = __fdiv_rn(1.0f, __fadd_rn(1.0f, expf(-xx)));
    a32 = fmaxf(sig, 0.1f);
  }
  float av[8]; int aj[8];
#pragma unroll
  for (int l = 0; l < 8; ++l) { av[l] = __shfl(a32, l, 64); aj[l] = __shfl(jl, l, 64); }
  if (lane == 0) {
    bool used[8] = {false,false,false,false,false,false,false,false};
    double dsum = 0.0;
#pragma unroll
    for (int k = 0; k < 5; ++k) {
      float bv = -2.0f; int bj = 0x7fffffff; int bs = -1;
#pragma unroll
      for (int s = 0; s < 8; ++s) {
        bool better = (!used[s]) && ((av[s] > bv) || (av[s] == bv && aj[s] < bj));
        bs = better ? s : bs;
        bv = better ? av[s] : bv;
        bj = better ? aj[s] : bj;
      }
#pragma unroll
      for (int s = 0; s < 8; ++s) used[s] = used[s] || (s == bs);
      top5i[row * 5 + k] = bj;
      top5v[row * 5 + k] = bv;
      dsum += (double)bv;
    }
    dinv[row] = (float)(1.0 / sqrt(dsum));
  }
}

// ---------- 10) Z = A_hat @ Hn, srow = rowsum(A_hat) ----------
__global__ void k_z(const float* __restrict__ Hn, const int* __restrict__ top5i,
                    const float* __restrict__ top5v, const float* __restrict__ dinv,
                    float* __restrict__ Z, float* __restrict__ srow) {
  __shared__ int sj[5];
  __shared__ float sw[5];
  int i = blockIdx.x, tid = threadIdx.x;
  if (tid < 5) {
    int j = top5i[i * 5 + tid];
    sj[tid] = j;
    sw[tid] = dinv[i] * top5v[i * 5 + tid] * dinv[j];
  }
  __syncthreads();
  double z = 0.0;
#pragma unroll
  for (int k = 0; k < 5; ++k) z += (double)sw[k] * (double)Hn[(size_t)sj[k] * DD + tid];
  Z[(size_t)i * DD + tid] = (float)z;
  if (tid == 0) srow[i] = sw[0] + sw[1] + sw[2] + sw[3] + sw[4];
}

// ---------- 11) out = LeakyReLU(Z @ W_out + srow*b_out) ----------
__global__ __launch_bounds__(256) void k_out2(const float* __restrict__ Z,
    const void* __restrict__ Wo, const void* __restrict__ bo,
    const float* __restrict__ srow, const int* __restrict__ pflag, void* __restrict__ outp) {
  int flag = *pflag;
  __shared__ float As[16][64];
  __shared__ float Bs[16][64];
  const int n0 = blockIdx.x * 64;
  const int i0 = blockIdx.y * 64;
  const int tid = threadIdx.x;
  const int tx = tid & 15, ty = tid >> 4;
  float acc[4][4];
#pragma unroll
  for (int r = 0; r < 4; ++r)
#pragma unroll
    for (int c = 0; c < 4; ++c) acc[r][c] = 0.0f;

  const int lm  = tid >> 2;
  const int lk4 = (tid & 3) * 4;
  const int kb  = tid >> 4;
  const int nb  = (tid & 15) * 4;

  for (int kc = 0; kc < DD; kc += 16) {
    __syncthreads();
    float4 a4 = *(const float4*)&Z[(size_t)(i0 + lm) * DD + kc + lk4];
    As[lk4 + 0][lm] = a4.x; As[lk4 + 1][lm] = a4.y;
    As[lk4 + 2][lm] = a4.z; As[lk4 + 3][lm] = a4.w;
#pragma unroll
    for (int u = 0; u < 4; ++u)
      Bs[kb][nb + u] = ldin(Wo, flag, (size_t)(kc + kb) * DD + n0 + nb + u);
    __syncthreads();
#pragma unroll 4
    for (int k = 0; k < 16; ++k) {
      float a0 = As[k][4*ty+0], a1 = As[k][4*ty+1], a2 = As[k][4*ty+2], a3 = As[k][4*ty+3];
      float b0 = Bs[k][4*tx+0], b1 = Bs[k][4*tx+1], b2 = Bs[k][4*tx+2], b3 = Bs[k][4*tx+3];
      acc[0][0] = fmaf(a0,b0,acc[0][0]); acc[0][1] = fmaf(a0,b1,acc[0][1]); acc[0][2] = fmaf(a0,b2,acc[0][2]); acc[0][3] = fmaf(a0,b3,acc[0][3]);
      acc[1][0] = fmaf(a1,b0,acc[1][0]); acc[1][1] = fmaf(a1,b1,acc[1][1]); acc[1][2] = fmaf(a1,b2,acc[1][2]); acc[1][3] = fmaf(a1,b3,acc[1][3]);
      acc[2][0] = fmaf(a2,b0,acc[2][0]); acc[2][1] = fmaf(a2,b1,acc[2][1]); acc[2][2] = fmaf(a2,b2,acc[2][2]); acc[2][3] = fmaf(a2,b3,acc[2][3]);
      acc[3][0] = fmaf(a3,b0,acc[3][0]); acc[3][1] = fmaf(a3,b1,acc[3][1]); acc[3][2] = fmaf(a3,b2,acc[3][2]); acc[3][3] = fmaf(a3,b3,acc[3][3]);
    }
  }
#pragma unroll
  for (int r = 0; r < 4; ++r) {
    int i = i0 + 4*ty + r;
    float s = srow[i];
#pragma unroll
    for (int c = 0; c < 4; ++c) {
      int col = n0 + 4*tx + c;
      float v = acc[r][c] + s * ldin(bo, flag, col);
      v = (v >= 0.0f) ? v : 0.01f * v;
      if (flag) ((bf16*)outp)[(size_t)i * DD + col] = __float2bfloat16(v);
      else      ((float*)outp)[(size_t)i * DD + col] = v;
    }
  }
}

// ---------- 12) zero-fill A output region ----------
__global__ void k_zeroA(void* __restrict__ d_out, const int* __restrict__ pflag) {
  int flag = *pflag;
  size_t esize = flag ? 2 : 4;
  uint4* base = (uint4*)((char*)d_out + (size_t)NN * DD * esize);
  size_t n16 = ((size_t)NN * NN * esize) >> 4;
  size_t idx = (size_t)blockIdx.x * 256 + threadIdx.x;
  size_t stride = (size_t)gridDim.x * 256;
  uint4 z; z.x = 0; z.y = 0; z.z = 0; z.w = 0;
  for (size_t i = idx; i < n16; i += stride) base[i] = z;
}

// ---------- 13) scatter masked A values ----------
__global__ void k_scatter(void* __restrict__ d_out, const int* __restrict__ pflag,
                          const int* __restrict__ top5i, const float* __restrict__ top5v) {
  int flag = *pflag;
  int t = blockIdx.x * 256 + threadIdx.x;
  if (t >= NN * 5) return;
  int row = t / 5, k = t % 5;
  int col = top5i[row * 5 + k];
  float v = top5v[row * 5 + k];
  size_t off = (size_t)row * NN + col;
  if (flag) ((bf16*)((char*)d_out + (size_t)NN * DD * 2))[off] = __float2bfloat16(v);
  else      ((float*)((char*)d_out + (size_t)NN * DD * 4))[off] = v;
}

extern "C" void kernel_launch(void* const* d_in, const int* in_sizes, int n_in,
                              void* d_out, int out_size, void* d_ws, size_t ws_size,
                              hipStream_t stream) {
  (void)in_sizes; (void)n_in; (void)out_size; (void)ws_size;
  const void* H     = d_in[0];
  const void* gamma = d_in[1];
  const void* beta  = d_in[2];
  const void* Wt    = d_in[3];
  const void* bt    = d_in[4];
  const void* Wo    = d_in[5];
  const void* bo    = d_in[6];

  // scratch zone inside the A-output region (valid in both dtype worlds), freed by k_zeroA
  const size_t MB = 1048576;
  char* zb = (char*)d_out + 8 * MB;
  float*    Hn32  = (float*)(zb + 0);              // 8 MiB
  float*    F1_32 = (float*)(zb + 8 * MB);         // 8 MiB (Hx -> F1 in place)
  ushort_t* F1hi  = (ushort_t*)(zb + 16 * MB);     // 4 MiB
  ushort_t* F1lo  = (ushort_t*)(zb + 20 * MB);     // 4 MiB
  float*    candv = (float*)(zb + 24 * MB);        // 1 MiB
  int*      candi = (int*)(zb + 25 * MB);          // 1 MiB
  float*    Z32   = (float*)(zb + 28 * MB);        // 8 MiB
  float*    HT    = (float*)(zb + 36 * MB);        // 8 MiB [DD][NN]
  float*    mu32  = (float*)(zb + 44 * MB);        // 1 KiB
  float*    rs32  = (float*)(zb + 44 * MB + 4096); // 1 KiB
  int*      cand8 = (int*)(zb + 44 * MB + 8192);   // 256 KiB
  float*    dinv  = (float*)(zb + 44 * MB + 270336);  // 32 KiB
  float*    srow  = (float*)(zb + 44 * MB + 303104);  // 32 KiB
  float*    Schunk= (float*)(zb + 48 * MB);        // 64 MiB [8192][2048], ends +112 < 124

  // d_ws: only what must survive k_zeroA
  char* ws = (char*)d_ws;
  int*   flag  = (int*)(ws + 0);
  int*   top5i = (int*)(ws + 256);       // 160 KiB
  float* top5v = (float*)(ws + 164096);  // 160 KiB

  k_detect<<<dim3(1), dim3(256), 0, stream>>>((const ushort_t*)H, flag);
  k_transposeH<<<dim3(128, 4), dim3(256), 0, stream>>>(H, flag, HT);
  k_statsT<<<dim3(64), dim3(256), 0, stream>>>(HT, mu32, rs32);
  k_bn32<<<dim3(NN), dim3(256), 0, stream>>>(H, flag, mu32, rs32, gamma, beta, Hn32);
  k_hx<<<dim3(NN), dim3(256), 0, stream>>>(Hn32, Wt, bt, flag, F1_32);
  k_norm32<<<dim3(2048), dim3(256), 0, stream>>>(F1_32, F1hi, F1lo);
  for (int jc = 0; jc < 4; ++jc) {
    k_gemm_s<<<dim3(16, 64), dim3(256), 0, stream>>>(F1hi, F1lo, jc, Schunk);
    k_scan<<<dim3(2048), dim3(256), 0, stream>>>(Schunk, jc, candv, candi);
  }
  k_merge<<<dim3(32), dim3(256), 0, stream>>>(candv, candi, cand8);
  k_rerank<<<dim3(2048), dim3(256), 0, stream>>>(F1_32, cand8, top5i, top5v, dinv);
  k_z<<<dim3(NN), dim3(256), 0, stream>>>(Hn32, top5i, top5v, dinv, Z32, srow);
  k_out2<<<dim3(4, 128), dim3(256), 0, stream>>>(Z32, Wo, bo, srow, flag, d_out);
  k_zeroA<<<dim3(8192), dim3(256), 0, stream>>>(d_out, flag);
  k_scatter<<<dim3(160), dim3(256), 0, stream>>>(d_out, flag, top5i, top5v);
}

// Round 7
// 1071.903 us; speedup vs baseline: 2.5758x; 1.2498x over previous
//
#include <hip/hip_runtime.h>
#include <hip/hip_bf16.h>
#include <cstdint>
#include <cstddef>

#define NN 8192
#define DD 256

using bf16 = __hip_bfloat16;
typedef unsigned short ushort_t;
typedef unsigned int uint32;
typedef short short8 __attribute__((ext_vector_type(8)));
typedef float f32x4 __attribute__((ext_vector_type(4)));

#define GL2LDS(g, l) __builtin_amdgcn_global_load_lds( \
  (const __attribute__((address_space(1))) void*)(g),  \
  (__attribute__((address_space(3))) void*)(l), 16, 0, 0)

// flag: 1 = inputs/outputs bf16, 0 = fp32
__device__ __forceinline__ float ldin(const void* p, int flag, size_t i) {
  return flag ? __bfloat162float(((const bf16*)p)[i]) : ((const float*)p)[i];
}

// ---------- top-8 insertion helpers ----------
__device__ __forceinline__ void ins8(float v, int jj, float (&lv)[8], int (&li)[8]) {
  if (v <= lv[7]) return;
  int cnt = 0;
#pragma unroll
  for (int s = 0; s < 8; ++s) cnt += (lv[s] >= v) ? 1 : 0;
#pragma unroll
  for (int s = 7; s >= 1; --s) {
    bool sh = (s > cnt);
    lv[s] = sh ? lv[s-1] : lv[s];
    li[s] = sh ? li[s-1] : li[s];
  }
#pragma unroll
  for (int s = 0; s < 8; ++s) if (s == cnt) { lv[s] = v; li[s] = jj; }
}

__device__ __forceinline__ void ins8t(float v, int jj, float (&lv)[8], int (&li)[8]) {
  bool lose = (lv[7] > v) || (lv[7] == v && li[7] < jj);
  if (lose) return;
  int cnt = 0;
#pragma unroll
  for (int s = 0; s < 8; ++s) cnt += ((lv[s] > v) || (lv[s] == v && li[s] < jj)) ? 1 : 0;
#pragma unroll
  for (int s = 7; s >= 1; --s) {
    bool sh = (s > cnt);
    lv[s] = sh ? lv[s-1] : lv[s];
    li[s] = sh ? li[s-1] : li[s];
  }
#pragma unroll
  for (int s = 0; s < 8; ++s) if (s == cnt) { lv[s] = v; li[s] = jj; }
}

// ---------- 0) dtype detection ----------
__global__ void k_detect(const ushort_t* __restrict__ Hu, int* __restrict__ flag) {
  __shared__ int cnt;
  if (threadIdx.x == 0) cnt = 0;
  __syncthreads();
  int sane = 0;
  for (int u = 0; u < 16; ++u) {
    int idx = 2 * (threadIdx.x * 16 + u);
    ushort_t h = Hu[idx];
    int e = (h >> 7) & 0xFF;
    sane += (e >= 113 && e <= 133) ? 1 : 0;
  }
  atomicAdd(&cnt, sane);
  __syncthreads();
  if (threadIdx.x == 0) *flag = (cnt > 2048) ? 1 : 0;
}

// ---------- 1) transpose H -> HT fp32 [DD][NN] ----------
__global__ void k_transposeH(const void* __restrict__ H, const int* __restrict__ pflag,
                             float* __restrict__ HT) {
  int flag = *pflag;
  __shared__ float tile[64][65];
  int i0 = blockIdx.x * 64;
  int c0 = blockIdx.y * 64;
  int tid = threadIdx.x;
  int r = tid >> 2, cb = (tid & 3) * 16;
#pragma unroll
  for (int u = 0; u < 16; ++u)
    tile[r][cb + u] = ldin(H, flag, (size_t)(i0 + r) * DD + c0 + cb + u);
  __syncthreads();
  int c = tid >> 2, rb = (tid & 3) * 16;
#pragma unroll
  for (int u4 = 0; u4 < 4; ++u4) {
    float4 t;
    t.x = tile[rb + 4*u4 + 0][c];
    t.y = tile[rb + 4*u4 + 1][c];
    t.z = tile[rb + 4*u4 + 2][c];
    t.w = tile[rb + 4*u4 + 3][c];
    *(float4*)&HT[(size_t)(c0 + c) * NN + i0 + rb + 4*u4] = t;
  }
}

// ---------- 2) BN stats: one column per block; bitwise sequential chains ----------
__global__ __launch_bounds__(256) void k_statsT(const float* __restrict__ HT,
                                                float* __restrict__ mu32, float* __restrict__ rs32) {
  __shared__ float buf[8192];   // 32 KiB: the whole column
  int c = blockIdx.x;
  int tid = threadIdx.x;
#pragma unroll
  for (int it = 0; it < 8; ++it) {
    int idx = it * 1024 + tid * 4;
    *(float4*)&buf[idx] = *(const float4*)&HT[(size_t)c * NN + idx];
  }
  __syncthreads();
  if (tid == 0) {
    float acc = 0.0f;
    for (int r = 0; r < 8192; r += 4) {
      float4 v = *(const float4*)&buf[r];
      acc = __fadd_rn(acc, v.x);
      acc = __fadd_rn(acc, v.y);
      acc = __fadd_rn(acc, v.z);
      acc = __fadd_rn(acc, v.w);
    }
    float mu = __fdiv_rn(acc, 8192.0f);
    float vacc = 0.0f;
    for (int r = 0; r < 8192; r += 4) {
      float4 v = *(const float4*)&buf[r];
      float d0 = __fsub_rn(v.x, mu); vacc = __fadd_rn(vacc, __fmul_rn(d0, d0));
      float d1 = __fsub_rn(v.y, mu); vacc = __fadd_rn(vacc, __fmul_rn(d1, d1));
      float d2 = __fsub_rn(v.z, mu); vacc = __fadd_rn(vacc, __fmul_rn(d2, d2));
      float d3 = __fsub_rn(v.w, mu); vacc = __fadd_rn(vacc, __fmul_rn(d3, d3));
    }
    float var = __fdiv_rn(vacc, 8192.0f);
    mu32[c] = mu;
    rs32[c] = __fdiv_rn(1.0f, sqrtf(__fadd_rn(var, 1e-5f)));
  }
}

// ---------- 3) BN apply ----------
__global__ void k_bn32(const void* __restrict__ H, const int* __restrict__ pflag,
                       const float* __restrict__ mu32, const float* __restrict__ rs32,
                       const void* __restrict__ gamma, const void* __restrict__ beta,
                       float* __restrict__ Hn) {
  int flag = *pflag;
  int i = blockIdx.x, c = threadIdx.x;
  float t = __fsub_rn(ldin(H, flag, (size_t)i * DD + c), mu32[c]);
  t = __fmul_rn(t, rs32[c]);
  t = __fmul_rn(t, ldin(gamma, flag, c));
  t = __fadd_rn(t, ldin(beta, flag, c));
  Hn[(size_t)i * DD + c] = t;
}

// ---------- 4) Hx = Hn @ W_theta + b_theta (sgemm mimic) ----------
__global__ __launch_bounds__(256) void k_hx(const float* __restrict__ Hn,
    const void* __restrict__ Wt, const void* __restrict__ bt, const int* __restrict__ pflag,
    float* __restrict__ Hx) {
  int flag = *pflag;
  __shared__ float sHn[DD];
  int i = blockIdx.x, n = threadIdx.x;
  sHn[n] = Hn[(size_t)i * DD + n];
  __syncthreads();
  float acc = 0.0f;
#pragma unroll 8
  for (int k = 0; k < DD; ++k)
    acc = fmaf(sHn[k], ldin(Wt, flag, (size_t)k * DD + n), acc);
  Hx[(size_t)i * DD + n] = __fadd_rn(acc, ldin(bt, flag, n));
}

// ---------- 5) row normalize (numpy pairwise mimic) + emit bf16 hi/lo split ----------
__global__ void k_norm32(float* __restrict__ F1, ushort_t* __restrict__ F1hi,
                         ushort_t* __restrict__ F1lo) {
  int w = threadIdx.x >> 6, lane = threadIdx.x & 63;
  int row = blockIdx.x * 4 + w;
  float* x = F1 + (size_t)row * DD;
  float part = 0.0f;
  if (lane < 16) {
    int base = (lane >> 3) * 128 + (lane & 7);
    float e0 = x[base];
    part = __fmul_rn(e0, e0);
#pragma unroll
    for (int t = 1; t < 16; ++t) {
      float e = x[base + 8 * t];
      part = __fadd_rn(part, __fmul_rn(e, e));
    }
  }
  float p[16];
#pragma unroll
  for (int s = 0; s < 16; ++s) p[s] = __shfl(part, s, 64);
  float P1 = __fadd_rn(__fadd_rn(__fadd_rn(p[0], p[1]), __fadd_rn(p[2], p[3])),
                       __fadd_rn(__fadd_rn(p[4], p[5]), __fadd_rn(p[6], p[7])));
  float P2 = __fadd_rn(__fadd_rn(__fadd_rn(p[8], p[9]), __fadd_rn(p[10], p[11])),
                       __fadd_rn(__fadd_rn(p[12], p[13]), __fadd_rn(p[14], p[15])));
  float nrm = fmaxf(sqrtf(__fadd_rn(P1, P2)), 1e-12f);
#pragma unroll
  for (int u = 0; u < 4; ++u) {
    float xn = __fdiv_rn(x[lane * 4 + u], nrm);
    x[lane * 4 + u] = xn;
    bf16 hi = __float2bfloat16(xn);
    float lo = __fsub_rn(xn, __bfloat162float(hi));
    F1hi[(size_t)row * DD + lane * 4 + u] = *(ushort_t*)&hi;
    bf16 lob = __float2bfloat16(lo);
    F1lo[(size_t)row * DD + lane * 4 + u] = *(ushort_t*)&lob;
  }
}

// ---------- 6) S-chunk GEMM via global_load_lds: S = hh + hl + lh ----------
// 128x128 tile, 4 waves (2x2 of 64x64). K-loop: 4 chunks of BK=64; per chunk all
// four tiles (A_hi, A_lo, B_hi, B_lo; 16 KiB each) staged direct-to-LDS with
// XOR swizzle (16B chunk g = cc ^ (row&7)); per ks: 16 ds_read_b128 + 48 MFMA.
__global__ __launch_bounds__(256) void k_gemm_s(
    const ushort_t* __restrict__ F1hi, const ushort_t* __restrict__ F1lo,
    int jc, float* __restrict__ S) {
  __shared__ __align__(16) ushort_t AH[8192];
  __shared__ __align__(16) ushort_t AL[8192];
  __shared__ __align__(16) ushort_t BH[8192];
  __shared__ __align__(16) ushort_t BL[8192];
  const int tid = threadIdx.x;
  const int w = tid >> 6, lane = tid & 63;
  const int quad = lane >> 4, l15 = lane & 15;
  const int wi = w >> 1, wj = w & 1;
  const int i0 = blockIdx.y * 128;
  const int j0loc = blockIdx.x * 128;
  const int j0 = jc * 2048 + j0loc;

  // staging lane geometry: slot s (uniform/instr) covers rows s*8..s*8+7;
  // lane -> row = s*8 + (lane>>3), 16B-chunk g = lane&7, source cc = g ^ (lane>>3)
  const int rofs = lane >> 3;                 // 0..7
  const int ccl  = (lane & 7) ^ rofs;         // swizzled k-chunk, slot-independent
  const int laneElem = rofs * DD + ccl * 8;   // ushort offset within (rowbase, kofs)

  f32x4 acc[4][4];
#pragma unroll
  for (int fr = 0; fr < 4; ++fr)
#pragma unroll
    for (int fc = 0; fc < 4; ++fc) acc[fr][fc] = (f32x4)0.0f;

  for (int chunk = 0; chunk < 4; ++chunk) {
    const int kofs = chunk * 64;
    __syncthreads();   // previous compute done before overwrite
#pragma unroll
    for (int q = 0; q < 4; ++q) {
      const int s = w * 4 + q;               // slot 0..15, uniform per wave
      const size_t ga = (size_t)(i0 + s * 8) * DD + kofs;
      const size_t gb = (size_t)(j0 + s * 8) * DD + kofs;
      GL2LDS(F1hi + ga + laneElem, &AH[s * 512]);
      GL2LDS(F1lo + ga + laneElem, &AL[s * 512]);
      GL2LDS(F1hi + gb + laneElem, &BH[s * 512]);
      GL2LDS(F1lo + gb + laneElem, &BL[s * 512]);
    }
    __syncthreads();   // loads visible
#pragma unroll
    for (int ks = 0; ks < 2; ++ks) {
      short8 ah[4], al[4], bh[4], bl[4];
#pragma unroll
      for (int fr = 0; fr < 4; ++fr) {
        int row = wi * 64 + fr * 16 + l15;
        int g = (ks * 4 + quad) ^ (row & 7);
        ah[fr] = *(const short8*)&AH[row * 64 + g * 8];
        al[fr] = *(const short8*)&AL[row * 64 + g * 8];
      }
#pragma unroll
      for (int fc = 0; fc < 4; ++fc) {
        int row = wj * 64 + fc * 16 + l15;
        int g = (ks * 4 + quad) ^ (row & 7);
        bh[fc] = *(const short8*)&BH[row * 64 + g * 8];
        bl[fc] = *(const short8*)&BL[row * 64 + g * 8];
      }
#pragma unroll
      for (int fr = 0; fr < 4; ++fr)
#pragma unroll
        for (int fc = 0; fc < 4; ++fc) {
          acc[fr][fc] = __builtin_amdgcn_mfma_f32_16x16x32_bf16(ah[fr], bh[fc], acc[fr][fc], 0, 0, 0);
          acc[fr][fc] = __builtin_amdgcn_mfma_f32_16x16x32_bf16(ah[fr], bl[fc], acc[fr][fc], 0, 0, 0);
          acc[fr][fc] = __builtin_amdgcn_mfma_f32_16x16x32_bf16(al[fr], bh[fc], acc[fr][fc], 0, 0, 0);
        }
    }
  }
  // epilogue: C layout col=l15, row=quad*4+reg
#pragma unroll
  for (int fr = 0; fr < 4; ++fr) {
#pragma unroll
    for (int reg = 0; reg < 4; ++reg) {
      int row = i0 + wi * 64 + fr * 16 + quad * 4 + reg;
#pragma unroll
      for (int fc = 0; fc < 4; ++fc) {
        int coll = j0loc + wj * 64 + fc * 16 + l15;
        S[(size_t)row * 2048 + coll] = acc[fr][fc][reg];
      }
    }
  }
}

// ---------- 7) per-chunk top-8 scan of S ----------
__global__ __launch_bounds__(256) void k_scan(const float* __restrict__ S, int jc,
                                              float* __restrict__ candv, int* __restrict__ candi) {
  int w = threadIdx.x >> 6, lane = threadIdx.x & 63;
  int row = blockIdx.x * 4 + w;
  const int jbase = jc * 2048;
  float lv[8]; int li[8];
#pragma unroll
  for (int e = 0; e < 8; ++e) { lv[e] = -3.0e38f; li[e] = 0x7fffffff; }
  const float* p = S + (size_t)row * 2048;
#pragma unroll
  for (int it = 0; it < 8; ++it) {
    int col = it * 256 + lane * 4;
    float4 v = *(const float4*)&p[col];
    ins8(v.x, jbase + col + 0, lv, li);
    ins8(v.y, jbase + col + 1, lv, li);
    ins8(v.z, jbase + col + 2, lv, li);
    ins8(v.w, jbase + col + 3, lv, li);
  }
#pragma unroll
  for (int m = 1; m <= 32; m <<= 1) {
    float tv[8]; int tj[8];
#pragma unroll
    for (int e = 0; e < 8; ++e) {
      tv[e] = __shfl_xor(lv[e], m, 64);
      tj[e] = __shfl_xor(li[e], m, 64);
    }
#pragma unroll
    for (int e = 0; e < 8; ++e) ins8t(tv[e], tj[e], lv, li);
  }
  if (lane == 0) {
    size_t base = ((size_t)row * 4 + jc) * 8;
#pragma unroll
    for (int e = 0; e < 8; ++e) { candv[base + e] = lv[e]; candi[base + e] = li[e]; }
  }
}

// ---------- 8) merge 4 per-chunk lists -> global top-8 per row ----------
__global__ void k_merge(const float* __restrict__ candv, const int* __restrict__ candi,
                        int* __restrict__ cand8) {
  int row = blockIdx.x * 256 + threadIdx.x;
  float bv[8]; int bj[8];
#pragma unroll
  for (int e = 0; e < 8; ++e) { bv[e] = -3.0e38f; bj[e] = 0x7fffffff; }
  for (int t = 0; t < 32; ++t) {
    float v = candv[(size_t)row * 32 + t];
    int j   = candi[(size_t)row * 32 + t];
    ins8t(v, j, bv, bj);
  }
#pragma unroll
  for (int e = 0; e < 8; ++e) cand8[row * 8 + e] = bj[e];
}

// ---------- 9) re-rank candidates with bitwise fp32-numpy mimic chain ----------
__global__ void k_rerank(const float* __restrict__ F1, const int* __restrict__ cand8,
                         int* __restrict__ top5i, float* __restrict__ top5v,
                         float* __restrict__ dinv) {
  int w = threadIdx.x >> 6, lane = threadIdx.x & 63;
  int row = blockIdx.x * 4 + w;
  int jl = 0x7fffffff;
  float a32 = -1.0f;
  if (lane < 8) {
    jl = cand8[row * 8 + lane];
    const float* xi = F1 + (size_t)row * DD;
    const float* xj = F1 + (size_t)jl * DD;
    float acc = 0.0f;
#pragma unroll 8
    for (int k = 0; k < DD; ++k)
      acc = fmaf(xi[k], xj[k], acc);
    float d = fminf(fmaxf(acc, -1.0f), 1.0f);
    float sam = acosf(d);
    float xx = expf(__fmul_rn(-0.2f, sam));
    float sig = __fdiv_rn(1.0f, __fadd_rn(1.0f, expf(-xx)));
    a32 = fmaxf(sig, 0.1f);
  }
  float av[8]; int aj[8];
#pragma unroll
  for (int l = 0; l < 8; ++l) { av[l] = __shfl(a32, l, 64); aj[l] = __shfl(jl, l, 64); }
  if (lane == 0) {
    bool used[8] = {false,false,false,false,false,false,false,false};
    double dsum = 0.0;
#pragma unroll
    for (int k = 0; k < 5; ++k) {
      float bv = -2.0f; int bj = 0x7fffffff; int bs = -1;
#pragma unroll
      for (int s = 0; s < 8; ++s) {
        bool better = (!used[s]) && ((av[s] > bv) || (av[s] == bv && aj[s] < bj));
        bs = better ? s : bs;
        bv = better ? av[s] : bv;
        bj = better ? aj[s] : bj;
      }
#pragma unroll
      for (int s = 0; s < 8; ++s) used[s] = used[s] || (s == bs);
      top5i[row * 5 + k] = bj;
      top5v[row * 5 + k] = bv;
      dsum += (double)bv;
    }
    dinv[row] = (float)(1.0 / sqrt(dsum));
  }
}

// ---------- 10) Z = A_hat @ Hn, srow = rowsum(A_hat) ----------
__global__ void k_z(const float* __restrict__ Hn, const int* __restrict__ top5i,
                    const float* __restrict__ top5v, const float* __restrict__ dinv,
                    float* __restrict__ Z, float* __restrict__ srow) {
  __shared__ int sj[5];
  __shared__ float sw[5];
  int i = blockIdx.x, tid = threadIdx.x;
  if (tid < 5) {
    int j = top5i[i * 5 + tid];
    sj[tid] = j;
    sw[tid] = dinv[i] * top5v[i * 5 + tid] * dinv[j];
  }
  __syncthreads();
  double z = 0.0;
#pragma unroll
  for (int k = 0; k < 5; ++k) z += (double)sw[k] * (double)Hn[(size_t)sj[k] * DD + tid];
  Z[(size_t)i * DD + tid] = (float)z;
  if (tid == 0) srow[i] = sw[0] + sw[1] + sw[2] + sw[3] + sw[4];
}

// ---------- 11) out = LeakyReLU(Z @ W_out + srow*b_out), row-per-block ----------
__global__ __launch_bounds__(256) void k_out3(const float* __restrict__ Z,
    const void* __restrict__ Wo, const void* __restrict__ bo,
    const float* __restrict__ srow, const int* __restrict__ pflag, void* __restrict__ outp) {
  int flag = *pflag;
  __shared__ float sZ[DD];
  int i = blockIdx.x, n = threadIdx.x;
  sZ[n] = Z[(size_t)i * DD + n];
  __syncthreads();
  float acc = 0.0f;
#pragma unroll 8
  for (int k = 0; k < DD; ++k)
    acc = fmaf(sZ[k], ldin(Wo, flag, (size_t)k * DD + n), acc);
  float v = acc + srow[i] * ldin(bo, flag, n);
  v = (v >= 0.0f) ? v : 0.01f * v;
  if (flag) ((bf16*)outp)[(size_t)i * DD + n] = __float2bfloat16(v);
  else      ((float*)outp)[(size_t)i * DD + n] = v;
}

// ---------- 12) zero-fill A output region ----------
__global__ void k_zeroA(void* __restrict__ d_out, const int* __restrict__ pflag) {
  int flag = *pflag;
  size_t esize = flag ? 2 : 4;
  uint4* base = (uint4*)((char*)d_out + (size_t)NN * DD * esize);
  size_t n16 = ((size_t)NN * NN * esize) >> 4;
  size_t idx = (size_t)blockIdx.x * 256 + threadIdx.x;
  size_t stride = (size_t)gridDim.x * 256;
  uint4 z; z.x = 0; z.y = 0; z.z = 0; z.w = 0;
  for (size_t i = idx; i < n16; i += stride) base[i] = z;
}

// ---------- 13) scatter masked A values ----------
__global__ void k_scatter(void* __restrict__ d_out, const int* __restrict__ pflag,
                          const int* __restrict__ top5i, const float* __restrict__ top5v) {
  int flag = *pflag;
  int t = blockIdx.x * 256 + threadIdx.x;
  if (t >= NN * 5) return;
  int row = t / 5, k = t % 5;
  int col = top5i[row * 5 + k];
  float v = top5v[row * 5 + k];
  size_t off = (size_t)row * NN + col;
  if (flag) ((bf16*)((char*)d_out + (size_t)NN * DD * 2))[off] = __float2bfloat16(v);
  else      ((float*)((char*)d_out + (size_t)NN * DD * 4))[off] = v;
}

extern "C" void kernel_launch(void* const* d_in, const int* in_sizes, int n_in,
                              void* d_out, int out_size, void* d_ws, size_t ws_size,
                              hipStream_t stream) {
  (void)in_sizes; (void)n_in; (void)out_size; (void)ws_size;
  const void* H     = d_in[0];
  const void* gamma = d_in[1];
  const void* beta  = d_in[2];
  const void* Wt    = d_in[3];
  const void* bt    = d_in[4];
  const void* Wo    = d_in[5];
  const void* bo    = d_in[6];

  // scratch zone inside the A-output region (valid in both dtype worlds), freed by k_zeroA
  const size_t MB = 1048576;
  char* zb = (char*)d_out + 8 * MB;
  float*    Hn32  = (float*)(zb + 0);              // 8 MiB
  float*    F1_32 = (float*)(zb + 8 * MB);         // 8 MiB (Hx -> F1 in place)
  ushort_t* F1hi  = (ushort_t*)(zb + 16 * MB);     // 4 MiB
  ushort_t* F1lo  = (ushort_t*)(zb + 20 * MB);     // 4 MiB
  float*    candv = (float*)(zb + 24 * MB);        // 1 MiB
  int*      candi = (int*)(zb + 25 * MB);          // 1 MiB
  float*    Z32   = (float*)(zb + 28 * MB);        // 8 MiB
  float*    HT    = (float*)(zb + 36 * MB);        // 8 MiB [DD][NN]
  float*    mu32  = (float*)(zb + 44 * MB);        // 1 KiB
  float*    rs32  = (float*)(zb + 44 * MB + 4096); // 1 KiB
  int*      cand8 = (int*)(zb + 44 * MB + 8192);   // 256 KiB
  float*    dinv  = (float*)(zb + 44 * MB + 270336);  // 32 KiB
  float*    srow  = (float*)(zb + 44 * MB + 303104);  // 32 KiB
  float*    Schunk= (float*)(zb + 48 * MB);        // 64 MiB [8192][2048], ends +112 < 124

  // d_ws: only what must survive k_zeroA
  char* ws = (char*)d_ws;
  int*   flag  = (int*)(ws + 0);
  int*   top5i = (int*)(ws + 256);       // 160 KiB
  float* top5v = (float*)(ws + 164096);  // 160 KiB

  k_detect<<<dim3(1), dim3(256), 0, stream>>>((const ushort_t*)H, flag);
  k_transposeH<<<dim3(128, 4), dim3(256), 0, stream>>>(H, flag, HT);
  k_statsT<<<dim3(256), dim3(256), 0, stream>>>(HT, mu32, rs32);
  k_bn32<<<dim3(NN), dim3(256), 0, stream>>>(H, flag, mu32, rs32, gamma, beta, Hn32);
  k_hx<<<dim3(NN), dim3(256), 0, stream>>>(Hn32, Wt, bt, flag, F1_32);
  k_norm32<<<dim3(2048), dim3(256), 0, stream>>>(F1_32, F1hi, F1lo);
  for (int jc = 0; jc < 4; ++jc) {
    k_gemm_s<<<dim3(16, 64), dim3(256), 0, stream>>>(F1hi, F1lo, jc, Schunk);
    k_scan<<<dim3(2048), dim3(256), 0, stream>>>(Schunk, jc, candv, candi);
  }
  k_merge<<<dim3(32), dim3(256), 0, stream>>>(candv, candi, cand8);
  k_rerank<<<dim3(2048), dim3(256), 0, stream>>>(F1_32, cand8, top5i, top5v, dinv);
  k_z<<<dim3(NN), dim3(256), 0, stream>>>(Hn32, top5i, top5v, dinv, Z32, srow);
  k_out3<<<dim3(NN), dim3(256), 0, stream>>>(Z32, Wo, bo, srow, flag, d_out);
  k_zeroA<<<dim3(8192), dim3(256), 0, stream>>>(d_out, flag);
  k_scatter<<<dim3(160), dim3(256), 0, stream>>>(d_out, flag, top5i, top5v);
}

// Round 8
// 930.755 us; speedup vs baseline: 2.9664x; 1.1516x over previous
//
#include <hip/hip_runtime.h>
#include <hip/hip_bf16.h>
#include <cstdint>
#include <cstddef>

#define NN 8192
#define DD 256

using bf16 = __hip_bfloat16;
typedef unsigned short ushort_t;
typedef unsigned int uint32;
typedef short short8 __attribute__((ext_vector_type(8)));
typedef float f32x4 __attribute__((ext_vector_type(4)));

#define GL2LDS(g, l) __builtin_amdgcn_global_load_lds( \
  (const __attribute__((address_space(1))) void*)(g),  \
  (__attribute__((address_space(3))) void*)(l), 16, 0, 0)

// flag: 1 = inputs/outputs bf16, 0 = fp32
__device__ __forceinline__ float ldin(const void* p, int flag, size_t i) {
  return flag ? __bfloat162float(((const bf16*)p)[i]) : ((const float*)p)[i];
}

// ---------- top-8 insertion helpers ----------
__device__ __forceinline__ void ins8(float v, int jj, float (&lv)[8], int (&li)[8]) {
  if (v <= lv[7]) return;
  int cnt = 0;
#pragma unroll
  for (int s = 0; s < 8; ++s) cnt += (lv[s] >= v) ? 1 : 0;
#pragma unroll
  for (int s = 7; s >= 1; --s) {
    bool sh = (s > cnt);
    lv[s] = sh ? lv[s-1] : lv[s];
    li[s] = sh ? li[s-1] : li[s];
  }
#pragma unroll
  for (int s = 0; s < 8; ++s) if (s == cnt) { lv[s] = v; li[s] = jj; }
}

__device__ __forceinline__ void ins8t(float v, int jj, float (&lv)[8], int (&li)[8]) {
  bool lose = (lv[7] > v) || (lv[7] == v && li[7] < jj);
  if (lose) return;
  int cnt = 0;
#pragma unroll
  for (int s = 0; s < 8; ++s) cnt += ((lv[s] > v) || (lv[s] == v && li[s] < jj)) ? 1 : 0;
#pragma unroll
  for (int s = 7; s >= 1; --s) {
    bool sh = (s > cnt);
    lv[s] = sh ? lv[s-1] : lv[s];
    li[s] = sh ? li[s-1] : li[s];
  }
#pragma unroll
  for (int s = 0; s < 8; ++s) if (s == cnt) { lv[s] = v; li[s] = jj; }
}

// lexicographic greater: (v desc, idx asc)
__device__ __forceinline__ bool lexgt(float va, int ia, float vb, int ib) {
  return (va > vb) || (va == vb && ia < ib);
}

// ---------- 0) dtype detection ----------
__global__ void k_detect(const ushort_t* __restrict__ Hu, int* __restrict__ flag) {
  __shared__ int cnt;
  if (threadIdx.x == 0) cnt = 0;
  __syncthreads();
  int sane = 0;
  for (int u = 0; u < 16; ++u) {
    int idx = 2 * (threadIdx.x * 16 + u);
    ushort_t h = Hu[idx];
    int e = (h >> 7) & 0xFF;
    sane += (e >= 113 && e <= 133) ? 1 : 0;
  }
  atomicAdd(&cnt, sane);
  __syncthreads();
  if (threadIdx.x == 0) *flag = (cnt > 2048) ? 1 : 0;
}

// ---------- 1) transpose H -> HT fp32 [DD][NN] ----------
__global__ void k_transposeH(const void* __restrict__ H, const int* __restrict__ pflag,
                             float* __restrict__ HT) {
  int flag = *pflag;
  __shared__ float tile[64][65];
  int i0 = blockIdx.x * 64;
  int c0 = blockIdx.y * 64;
  int tid = threadIdx.x;
  int r = tid >> 2, cb = (tid & 3) * 16;
#pragma unroll
  for (int u = 0; u < 16; ++u)
    tile[r][cb + u] = ldin(H, flag, (size_t)(i0 + r) * DD + c0 + cb + u);
  __syncthreads();
  int c = tid >> 2, rb = (tid & 3) * 16;
#pragma unroll
  for (int u4 = 0; u4 < 4; ++u4) {
    float4 t;
    t.x = tile[rb + 4*u4 + 0][c];
    t.y = tile[rb + 4*u4 + 1][c];
    t.z = tile[rb + 4*u4 + 2][c];
    t.w = tile[rb + 4*u4 + 3][c];
    *(float4*)&HT[(size_t)(c0 + c) * NN + i0 + rb + 4*u4] = t;
  }
}

// ---------- 2) BN stats: one column per block; bitwise sequential chains,
//             explicitly pipelined (batch 8 float4 loads, then 32 chained adds) ----------
__global__ __launch_bounds__(256) void k_statsT(const float* __restrict__ HT,
                                                float* __restrict__ mu32, float* __restrict__ rs32) {
  __shared__ float buf[8192];   // 32 KiB: the whole column
  int c = blockIdx.x;
  int tid = threadIdx.x;
#pragma unroll
  for (int it = 0; it < 8; ++it) {
    int idx = it * 1024 + tid * 4;
    *(float4*)&buf[idx] = *(const float4*)&HT[(size_t)c * NN + idx];
  }
  __syncthreads();
  if (tid == 0) {
    float acc = 0.0f;
    for (int r = 0; r < 8192; r += 32) {
      float4 v[8];
#pragma unroll
      for (int q = 0; q < 8; ++q) v[q] = *(const float4*)&buf[r + q * 4];
#pragma unroll
      for (int q = 0; q < 8; ++q) {
        acc = __fadd_rn(acc, v[q].x);
        acc = __fadd_rn(acc, v[q].y);
        acc = __fadd_rn(acc, v[q].z);
        acc = __fadd_rn(acc, v[q].w);
      }
    }
    float mu = __fdiv_rn(acc, 8192.0f);
    float vacc = 0.0f;
    for (int r = 0; r < 8192; r += 32) {
      float4 v[8];
#pragma unroll
      for (int q = 0; q < 8; ++q) v[q] = *(const float4*)&buf[r + q * 4];
#pragma unroll
      for (int q = 0; q < 8; ++q) {
        float d0 = __fsub_rn(v[q].x, mu); vacc = __fadd_rn(vacc, __fmul_rn(d0, d0));
        float d1 = __fsub_rn(v[q].y, mu); vacc = __fadd_rn(vacc, __fmul_rn(d1, d1));
        float d2 = __fsub_rn(v[q].z, mu); vacc = __fadd_rn(vacc, __fmul_rn(d2, d2));
        float d3 = __fsub_rn(v[q].w, mu); vacc = __fadd_rn(vacc, __fmul_rn(d3, d3));
      }
    }
    float var = __fdiv_rn(vacc, 8192.0f);
    mu32[c] = mu;
    rs32[c] = __fdiv_rn(1.0f, sqrtf(__fadd_rn(var, 1e-5f)));
  }
}

// ---------- 3) BN apply ----------
__global__ void k_bn32(const void* __restrict__ H, const int* __restrict__ pflag,
                       const float* __restrict__ mu32, const float* __restrict__ rs32,
                       const void* __restrict__ gamma, const void* __restrict__ beta,
                       float* __restrict__ Hn) {
  int flag = *pflag;
  int i = blockIdx.x, c = threadIdx.x;
  float t = __fsub_rn(ldin(H, flag, (size_t)i * DD + c), mu32[c]);
  t = __fmul_rn(t, rs32[c]);
  t = __fmul_rn(t, ldin(gamma, flag, c));
  t = __fadd_rn(t, ldin(beta, flag, c));
  Hn[(size_t)i * DD + c] = t;
}

// ---------- 4) Hx = Hn @ W_theta + b_theta (sgemm mimic) ----------
__global__ __launch_bounds__(256) void k_hx(const float* __restrict__ Hn,
    const void* __restrict__ Wt, const void* __restrict__ bt, const int* __restrict__ pflag,
    float* __restrict__ Hx) {
  int flag = *pflag;
  __shared__ float sHn[DD];
  int i = blockIdx.x, n = threadIdx.x;
  sHn[n] = Hn[(size_t)i * DD + n];
  __syncthreads();
  float acc = 0.0f;
#pragma unroll 8
  for (int k = 0; k < DD; ++k)
    acc = fmaf(sHn[k], ldin(Wt, flag, (size_t)k * DD + n), acc);
  Hx[(size_t)i * DD + n] = __fadd_rn(acc, ldin(bt, flag, n));
}

// ---------- 5) row normalize (numpy pairwise mimic) + emit bf16 hi/lo split ----------
__global__ void k_norm32(float* __restrict__ F1, ushort_t* __restrict__ F1hi,
                         ushort_t* __restrict__ F1lo) {
  int w = threadIdx.x >> 6, lane = threadIdx.x & 63;
  int row = blockIdx.x * 4 + w;
  float* x = F1 + (size_t)row * DD;
  float part = 0.0f;
  if (lane < 16) {
    int base = (lane >> 3) * 128 + (lane & 7);
    float e0 = x[base];
    part = __fmul_rn(e0, e0);
#pragma unroll
    for (int t = 1; t < 16; ++t) {
      float e = x[base + 8 * t];
      part = __fadd_rn(part, __fmul_rn(e, e));
    }
  }
  float p[16];
#pragma unroll
  for (int s = 0; s < 16; ++s) p[s] = __shfl(part, s, 64);
  float P1 = __fadd_rn(__fadd_rn(__fadd_rn(p[0], p[1]), __fadd_rn(p[2], p[3])),
                       __fadd_rn(__fadd_rn(p[4], p[5]), __fadd_rn(p[6], p[7])));
  float P2 = __fadd_rn(__fadd_rn(__fadd_rn(p[8], p[9]), __fadd_rn(p[10], p[11])),
                       __fadd_rn(__fadd_rn(p[12], p[13]), __fadd_rn(p[14], p[15])));
  float nrm = fmaxf(sqrtf(__fadd_rn(P1, P2)), 1e-12f);
#pragma unroll
  for (int u = 0; u < 4; ++u) {
    float xn = __fdiv_rn(x[lane * 4 + u], nrm);
    x[lane * 4 + u] = xn;
    bf16 hi = __float2bfloat16(xn);
    float lo = __fsub_rn(xn, __bfloat162float(hi));
    F1hi[(size_t)row * DD + lane * 4 + u] = *(ushort_t*)&hi;
    bf16 lob = __float2bfloat16(lo);
    F1lo[(size_t)row * DD + lane * 4 + u] = *(ushort_t*)&lob;
  }
}

// ---------- 6) S-chunk GEMM via global_load_lds: S = hh + hl + lh ----------
// 128x128 tile, 4 waves (2x2 of 64x64). BK=32, 8 chunks; 32 KiB LDS -> 4 blocks/CU.
__global__ __launch_bounds__(256) void k_gemm_s(
    const ushort_t* __restrict__ F1hi, const ushort_t* __restrict__ F1lo,
    int jc, float* __restrict__ S) {
  __shared__ __align__(16) ushort_t AH[4096];
  __shared__ __align__(16) ushort_t AL[4096];
  __shared__ __align__(16) ushort_t BH[4096];
  __shared__ __align__(16) ushort_t BL[4096];
  const int tid = threadIdx.x;
  const int w = tid >> 6, lane = tid & 63;
  const int quad = lane >> 4, l15 = lane & 15;
  const int wi = w >> 1, wj = w & 1;
  const int i0 = blockIdx.y * 128;
  const int j0loc = blockIdx.x * 128;
  const int j0 = jc * 2048 + j0loc;

  // staging: slot s covers 16 rows (1 KiB); lane -> row = s*16 + (lane>>2),
  // dest 16B-chunk d = lane&3, source chunk cc = d ^ ((lane>>2)&3)
  const int rofs = lane >> 2;                  // 0..15
  const int ccl  = (lane & 3) ^ (rofs & 3);    // swizzled k-chunk (4 per row of 64B)
  const int laneElem = rofs * DD + ccl * 8;

  f32x4 acc[4][4];
#pragma unroll
  for (int fr = 0; fr < 4; ++fr)
#pragma unroll
    for (int fc = 0; fc < 4; ++fc) acc[fr][fc] = (f32x4)0.0f;

  for (int chunk = 0; chunk < 8; ++chunk) {
    const int kofs = chunk * 32;
    __syncthreads();
#pragma unroll
    for (int q = 0; q < 2; ++q) {
      const int s = w * 2 + q;               // slot 0..7, 16 rows each
      const size_t ga = (size_t)(i0 + s * 16) * DD + kofs;
      const size_t gb = (size_t)(j0 + s * 16) * DD + kofs;
      GL2LDS(F1hi + ga + laneElem, &AH[s * 512]);
      GL2LDS(F1lo + ga + laneElem, &AL[s * 512]);
      GL2LDS(F1hi + gb + laneElem, &BH[s * 512]);
      GL2LDS(F1lo + gb + laneElem, &BL[s * 512]);
    }
    __syncthreads();
    short8 ah[4], al[4], bh[4], bl[4];
#pragma unroll
    for (int fr = 0; fr < 4; ++fr) {
      int row = wi * 64 + fr * 16 + l15;
      int g = quad ^ (row & 3);
      ah[fr] = *(const short8*)&AH[row * 32 + g * 8];
      al[fr] = *(const short8*)&AL[row * 32 + g * 8];
    }
#pragma unroll
    for (int fc = 0; fc < 4; ++fc) {
      int row = wj * 64 + fc * 16 + l15;
      int g = quad ^ (row & 3);
      bh[fc] = *(const short8*)&BH[row * 32 + g * 8];
      bl[fc] = *(const short8*)&BL[row * 32 + g * 8];
    }
#pragma unroll
    for (int fr = 0; fr < 4; ++fr)
#pragma unroll
      for (int fc = 0; fc < 4; ++fc) {
        acc[fr][fc] = __builtin_amdgcn_mfma_f32_16x16x32_bf16(ah[fr], bh[fc], acc[fr][fc], 0, 0, 0);
        acc[fr][fc] = __builtin_amdgcn_mfma_f32_16x16x32_bf16(ah[fr], bl[fc], acc[fr][fc], 0, 0, 0);
        acc[fr][fc] = __builtin_amdgcn_mfma_f32_16x16x32_bf16(al[fr], bh[fc], acc[fr][fc], 0, 0, 0);
      }
  }
  // epilogue: C layout col=l15, row=quad*4+reg
#pragma unroll
  for (int fr = 0; fr < 4; ++fr) {
#pragma unroll
    for (int reg = 0; reg < 4; ++reg) {
      int row = i0 + wi * 64 + fr * 16 + quad * 4 + reg;
#pragma unroll
      for (int fc = 0; fc < 4; ++fc) {
        int coll = j0loc + wj * 64 + fc * 16 + l15;
        S[(size_t)row * 2048 + coll] = acc[fr][fc][reg];
      }
    }
  }
}

// ---------- 7) per-chunk top-8 scan of S; bitonic butterfly merge ----------
__global__ __launch_bounds__(256) void k_scan(const float* __restrict__ S, int jc,
                                              float* __restrict__ candv, int* __restrict__ candi) {
  int w = threadIdx.x >> 6, lane = threadIdx.x & 63;
  int row = blockIdx.x * 4 + w;
  const int jbase = jc * 2048;
  float lv[8]; int li[8];
#pragma unroll
  for (int e = 0; e < 8; ++e) { lv[e] = -3.0e38f; li[e] = 0x7fffffff; }
  const float* p = S + (size_t)row * 2048;
#pragma unroll
  for (int it = 0; it < 8; ++it) {
    int col = it * 256 + lane * 4;
    float4 v = *(const float4*)&p[col];
    ins8(v.x, jbase + col + 0, lv, li);
    ins8(v.y, jbase + col + 1, lv, li);
    ins8(v.z, jbase + col + 2, lv, li);
    ins8(v.w, jbase + col + 3, lv, li);
  }
  // butterfly with bitonic top-8 merge (lists stay sorted desc, ties idx-asc)
#pragma unroll
  for (int m = 1; m <= 32; m <<= 1) {
    float bv[8]; int bi[8];
#pragma unroll
    for (int e = 0; e < 8; ++e) {
      bv[e] = __shfl_xor(lv[e], m, 64);
      bi[e] = __shfl_xor(li[e], m, 64);
    }
    // stage 1: m[k] = max(a[k], b[7-k]) -> 8 largest (bitonic)
#pragma unroll
    for (int e = 0; e < 8; ++e) {
      bool t = lexgt(lv[e], li[e], bv[7 - e], bi[7 - e]);
      lv[e] = t ? lv[e] : bv[7 - e];
      li[e] = t ? li[e] : bi[7 - e];
    }
    // bitonic sort desc: distances 4, 2, 1
#pragma unroll
    for (int d = 4; d >= 1; d >>= 1) {
#pragma unroll
      for (int e = 0; e < 8; ++e) {
        if ((e & d) == 0) {
          int f = e + d;
          bool sw = lexgt(lv[f], li[f], lv[e], li[e]);
          float tv = lv[e]; int ti = li[e];
          lv[e] = sw ? lv[f] : lv[e];  li[e] = sw ? li[f] : li[e];
          lv[f] = sw ? tv : lv[f];     li[f] = sw ? ti : li[f];
        }
      }
    }
  }
  if (lane == 0) {
    size_t base = ((size_t)row * 4 + jc) * 8;
#pragma unroll
    for (int e = 0; e < 8; ++e) { candv[base + e] = lv[e]; candi[base + e] = li[e]; }
  }
}

// ---------- 8) merge 4 per-chunk lists -> global top-8 per row ----------
__global__ void k_merge(const float* __restrict__ candv, const int* __restrict__ candi,
                        int* __restrict__ cand8) {
  int row = blockIdx.x * 256 + threadIdx.x;
  float bv[8]; int bj[8];
#pragma unroll
  for (int e = 0; e < 8; ++e) { bv[e] = -3.0e38f; bj[e] = 0x7fffffff; }
  for (int t = 0; t < 32; ++t) {
    float v = candv[(size_t)row * 32 + t];
    int j   = candi[(size_t)row * 32 + t];
    ins8t(v, j, bv, bj);
  }
#pragma unroll
  for (int e = 0; e < 8; ++e) cand8[row * 8 + e] = bj[e];
}

// ---------- 9) re-rank candidates with bitwise fp32-numpy mimic chain ----------
__global__ void k_rerank(const float* __restrict__ F1, const int* __restrict__ cand8,
                         int* __restrict__ top5i, float* __restrict__ top5v,
                         float* __restrict__ dinv) {
  int w = threadIdx.x >> 6, lane = threadIdx.x & 63;
  int row = blockIdx.x * 4 + w;
  int jl = 0x7fffffff;
  float a32 = -1.0f;
  if (lane < 8) {
    jl = cand8[row * 8 + lane];
    const float* xi = F1 + (size_t)row * DD;
    const float* xj = F1 + (size_t)jl * DD;
    float acc = 0.0f;
#pragma unroll 8
    for (int k = 0; k < DD; ++k)
      acc = fmaf(xi[k], xj[k], acc);
    float d = fminf(fmaxf(acc, -1.0f), 1.0f);
    float sam = acosf(d);
    float xx = expf(__fmul_rn(-0.2f, sam));
    float sig = __fdiv_rn(1.0f, __fadd_rn(1.0f, expf(-xx)));
    a32 = fmaxf(sig, 0.1f);
  }
  float av[8]; int aj[8];
#pragma unroll
  for (int l = 0; l < 8; ++l) { av[l] = __shfl(a32, l, 64); aj[l] = __shfl(jl, l, 64); }
  if (lane == 0) {
    bool used[8] = {false,false,false,false,false,false,false,false};
    double dsum = 0.0;
#pragma unroll
    for (int k = 0; k < 5; ++k) {
      float bv = -2.0f; int bj = 0x7fffffff; int bs = -1;
#pragma unroll
      for (int s = 0; s < 8; ++s) {
        bool better = (!used[s]) && ((av[s] > bv) || (av[s] == bv && aj[s] < bj));
        bs = better ? s : bs;
        bv = better ? av[s] : bv;
        bj = better ? aj[s] : bj;
      }
#pragma unroll
      for (int s = 0; s < 8; ++s) used[s] = used[s] || (s == bs);
      top5i[row * 5 + k] = bj;
      top5v[row * 5 + k] = bv;
      dsum += (double)bv;
    }
    dinv[row] = (float)(1.0 / sqrt(dsum));
  }
}

// ---------- 10) Z = A_hat @ Hn, srow = rowsum(A_hat) ----------
__global__ void k_z(const float* __restrict__ Hn, const int* __restrict__ top5i,
                    const float* __restrict__ top5v, const float* __restrict__ dinv,
                    float* __restrict__ Z, float* __restrict__ srow) {
  __shared__ int sj[5];
  __shared__ float sw[5];
  int i = blockIdx.x, tid = threadIdx.x;
  if (tid < 5) {
    int j = top5i[i * 5 + tid];
    sj[tid] = j;
    sw[tid] = dinv[i] * top5v[i * 5 + tid] * dinv[j];
  }
  __syncthreads();
  double z = 0.0;
#pragma unroll
  for (int k = 0; k < 5; ++k) z += (double)sw[k] * (double)Hn[(size_t)sj[k] * DD + tid];
  Z[(size_t)i * DD + tid] = (float)z;
  if (tid == 0) srow[i] = sw[0] + sw[1] + sw[2] + sw[3] + sw[4];
}

// ---------- 11) out = LeakyReLU(Z @ W_out + srow*b_out), row-per-block ----------
__global__ __launch_bounds__(256) void k_out3(const float* __restrict__ Z,
    const void* __restrict__ Wo, const void* __restrict__ bo,
    const float* __restrict__ srow, const int* __restrict__ pflag, void* __restrict__ outp) {
  int flag = *pflag;
  __shared__ float sZ[DD];
  int i = blockIdx.x, n = threadIdx.x;
  sZ[n] = Z[(size_t)i * DD + n];
  __syncthreads();
  float acc = 0.0f;
#pragma unroll 8
  for (int k = 0; k < DD; ++k)
    acc = fmaf(sZ[k], ldin(Wo, flag, (size_t)k * DD + n), acc);
  float v = acc + srow[i] * ldin(bo, flag, n);
  v = (v >= 0.0f) ? v : 0.01f * v;
  if (flag) ((bf16*)outp)[(size_t)i * DD + n] = __float2bfloat16(v);
  else      ((float*)outp)[(size_t)i * DD + n] = v;
}

// ---------- 12) zero-fill A output region ----------
__global__ void k_zeroA(void* __restrict__ d_out, const int* __restrict__ pflag) {
  int flag = *pflag;
  size_t esize = flag ? 2 : 4;
  uint4* base = (uint4*)((char*)d_out + (size_t)NN * DD * esize);
  size_t n16 = ((size_t)NN * NN * esize) >> 4;
  size_t idx = (size_t)blockIdx.x * 256 + threadIdx.x;
  size_t stride = (size_t)gridDim.x * 256;
  uint4 z; z.x = 0; z.y = 0; z.z = 0; z.w = 0;
  for (size_t i = idx; i < n16; i += stride) base[i] = z;
}

// ---------- 13) scatter masked A values ----------
__global__ void k_scatter(void* __restrict__ d_out, const int* __restrict__ pflag,
                          const int* __restrict__ top5i, const float* __restrict__ top5v) {
  int flag = *pflag;
  int t = blockIdx.x * 256 + threadIdx.x;
  if (t >= NN * 5) return;
  int row = t / 5, k = t % 5;
  int col = top5i[row * 5 + k];
  float v = top5v[row * 5 + k];
  size_t off = (size_t)row * NN + col;
  if (flag) ((bf16*)((char*)d_out + (size_t)NN * DD * 2))[off] = __float2bfloat16(v);
  else      ((float*)((char*)d_out + (size_t)NN * DD * 4))[off] = v;
}

extern "C" void kernel_launch(void* const* d_in, const int* in_sizes, int n_in,
                              void* d_out, int out_size, void* d_ws, size_t ws_size,
                              hipStream_t stream) {
  (void)in_sizes; (void)n_in; (void)out_size; (void)ws_size;
  const void* H     = d_in[0];
  const void* gamma = d_in[1];
  const void* beta  = d_in[2];
  const void* Wt    = d_in[3];
  const void* bt    = d_in[4];
  const void* Wo    = d_in[5];
  const void* bo    = d_in[6];

  // scratch zone inside the A-output region (valid in both dtype worlds), freed by k_zeroA
  const size_t MB = 1048576;
  char* zb = (char*)d_out + 8 * MB;
  float*    Hn32  = (float*)(zb + 0);              // 8 MiB
  float*    F1_32 = (float*)(zb + 8 * MB);         // 8 MiB (Hx -> F1 in place)
  ushort_t* F1hi  = (ushort_t*)(zb + 16 * MB);     // 4 MiB
  ushort_t* F1lo  = (ushort_t*)(zb + 20 * MB);     // 4 MiB
  float*    candv = (float*)(zb + 24 * MB);        // 1 MiB
  int*      candi = (int*)(zb + 25 * MB);          // 1 MiB
  float*    Z32   = (float*)(zb + 28 * MB);        // 8 MiB
  float*    HT    = (float*)(zb + 36 * MB);        // 8 MiB [DD][NN]
  float*    mu32  = (float*)(zb + 44 * MB);        // 1 KiB
  float*    rs32  = (float*)(zb + 44 * MB + 4096); // 1 KiB
  int*      cand8 = (int*)(zb + 44 * MB + 8192);   // 256 KiB
  float*    dinv  = (float*)(zb + 44 * MB + 270336);  // 32 KiB
  float*    srow  = (float*)(zb + 44 * MB + 303104);  // 32 KiB
  float*    Schunk= (float*)(zb + 48 * MB);        // 64 MiB [8192][2048], ends +112 < 124

  // d_ws: only what must survive k_zeroA
  char* ws = (char*)d_ws;
  int*   flag  = (int*)(ws + 0);
  int*   top5i = (int*)(ws + 256);       // 160 KiB
  float* top5v = (float*)(ws + 164096);  // 160 KiB

  k_detect<<<dim3(1), dim3(256), 0, stream>>>((const ushort_t*)H, flag);
  k_transposeH<<<dim3(128, 4), dim3(256), 0, stream>>>(H, flag, HT);
  k_statsT<<<dim3(256), dim3(256), 0, stream>>>(HT, mu32, rs32);
  k_bn32<<<dim3(NN), dim3(256), 0, stream>>>(H, flag, mu32, rs32, gamma, beta, Hn32);
  k_hx<<<dim3(NN), dim3(256), 0, stream>>>(Hn32, Wt, bt, flag, F1_32);
  k_norm32<<<dim3(2048), dim3(256), 0, stream>>>(F1_32, F1hi, F1lo);
  for (int jc = 0; jc < 4; ++jc) {
    k_gemm_s<<<dim3(16, 64), dim3(256), 0, stream>>>(F1hi, F1lo, jc, Schunk);
    k_scan<<<dim3(2048), dim3(256), 0, stream>>>(Schunk, jc, candv, candi);
  }
  k_merge<<<dim3(32), dim3(256), 0, stream>>>(candv, candi, cand8);
  k_rerank<<<dim3(2048), dim3(256), 0, stream>>>(F1_32, cand8, top5i, top5v, dinv);
  k_z<<<dim3(NN), dim3(256), 0, stream>>>(Hn32, top5i, top5v, dinv, Z32, srow);
  k_out3<<<dim3(NN), dim3(256), 0, stream>>>(Z32, Wo, bo, srow, flag, d_out);
  k_zeroA<<<dim3(8192), dim3(256), 0, stream>>>(d_out, flag);
  k_scatter<<<dim3(160), dim3(256), 0, stream>>>(d_out, flag, top5i, top5v);
}

// Round 9
// 838.380 us; speedup vs baseline: 3.2933x; 1.1102x over previous
//
#include <hip/hip_runtime.h>
#include <hip/hip_bf16.h>
#include <cstdint>
#include <cstddef>

#define NN 8192
#define DD 256

using bf16 = __hip_bfloat16;
typedef unsigned short ushort_t;
typedef unsigned int uint32;
typedef short short8 __attribute__((ext_vector_type(8)));
typedef float f32x4 __attribute__((ext_vector_type(4)));

#define GL2LDS(g, l) __builtin_amdgcn_global_load_lds( \
  (const __attribute__((address_space(1))) void*)(g),  \
  (__attribute__((address_space(3))) void*)(l), 16, 0, 0)

// flag: 1 = inputs/outputs bf16, 0 = fp32
__device__ __forceinline__ float ldin(const void* p, int flag, size_t i) {
  return flag ? __bfloat162float(((const bf16*)p)[i]) : ((const float*)p)[i];
}

// ---------- top-8 insertion helpers ----------
__device__ __forceinline__ void ins8(float v, int jj, float (&lv)[8], int (&li)[8]) {
  if (v <= lv[7]) return;
  int cnt = 0;
#pragma unroll
  for (int s = 0; s < 8; ++s) cnt += (lv[s] >= v) ? 1 : 0;
#pragma unroll
  for (int s = 7; s >= 1; --s) {
    bool sh = (s > cnt);
    lv[s] = sh ? lv[s-1] : lv[s];
    li[s] = sh ? li[s-1] : li[s];
  }
#pragma unroll
  for (int s = 0; s < 8; ++s) if (s == cnt) { lv[s] = v; li[s] = jj; }
}

__device__ __forceinline__ void ins8t(float v, int jj, float (&lv)[8], int (&li)[8]) {
  bool lose = (lv[7] > v) || (lv[7] == v && li[7] < jj);
  if (lose) return;
  int cnt = 0;
#pragma unroll
  for (int s = 0; s < 8; ++s) cnt += ((lv[s] > v) || (lv[s] == v && li[s] < jj)) ? 1 : 0;
#pragma unroll
  for (int s = 7; s >= 1; --s) {
    bool sh = (s > cnt);
    lv[s] = sh ? lv[s-1] : lv[s];
    li[s] = sh ? li[s-1] : li[s];
  }
#pragma unroll
  for (int s = 0; s < 8; ++s) if (s == cnt) { lv[s] = v; li[s] = jj; }
}

// lexicographic greater: (v desc, idx asc)
__device__ __forceinline__ bool lexgt(float va, int ia, float vb, int ib) {
  return (va > vb) || (va == vb && ia < ib);
}

// ---------- 0) dtype detection ----------
__global__ void k_detect(const ushort_t* __restrict__ Hu, int* __restrict__ flag) {
  __shared__ int cnt;
  if (threadIdx.x == 0) cnt = 0;
  __syncthreads();
  int sane = 0;
  for (int u = 0; u < 16; ++u) {
    int idx = 2 * (threadIdx.x * 16 + u);
    ushort_t h = Hu[idx];
    int e = (h >> 7) & 0xFF;
    sane += (e >= 113 && e <= 133) ? 1 : 0;
  }
  atomicAdd(&cnt, sane);
  __syncthreads();
  if (threadIdx.x == 0) *flag = (cnt > 2048) ? 1 : 0;
}

// ---------- 1) transpose H -> HT fp32 [DD][NN] ----------
__global__ void k_transposeH(const void* __restrict__ H, const int* __restrict__ pflag,
                             float* __restrict__ HT) {
  int flag = *pflag;
  __shared__ float tile[64][65];
  int i0 = blockIdx.x * 64;
  int c0 = blockIdx.y * 64;
  int tid = threadIdx.x;
  int r = tid >> 2, cb = (tid & 3) * 16;
#pragma unroll
  for (int u = 0; u < 16; ++u)
    tile[r][cb + u] = ldin(H, flag, (size_t)(i0 + r) * DD + c0 + cb + u);
  __syncthreads();
  int c = tid >> 2, rb = (tid & 3) * 16;
#pragma unroll
  for (int u4 = 0; u4 < 4; ++u4) {
    float4 t;
    t.x = tile[rb + 4*u4 + 0][c];
    t.y = tile[rb + 4*u4 + 1][c];
    t.z = tile[rb + 4*u4 + 2][c];
    t.w = tile[rb + 4*u4 + 3][c];
    *(float4*)&HT[(size_t)(c0 + c) * NN + i0 + rb + 4*u4] = t;
  }
}

// ---------- 2) BN stats: one column per block; bitwise sequential chains ----------
__global__ __launch_bounds__(256) void k_statsT(const float* __restrict__ HT,
                                                float* __restrict__ mu32, float* __restrict__ rs32) {
  __shared__ float buf[8192];
  int c = blockIdx.x;
  int tid = threadIdx.x;
#pragma unroll
  for (int it = 0; it < 8; ++it) {
    int idx = it * 1024 + tid * 4;
    *(float4*)&buf[idx] = *(const float4*)&HT[(size_t)c * NN + idx];
  }
  __syncthreads();
  if (tid == 0) {
    float acc = 0.0f;
    for (int r = 0; r < 8192; r += 32) {
      float4 v[8];
#pragma unroll
      for (int q = 0; q < 8; ++q) v[q] = *(const float4*)&buf[r + q * 4];
#pragma unroll
      for (int q = 0; q < 8; ++q) {
        acc = __fadd_rn(acc, v[q].x);
        acc = __fadd_rn(acc, v[q].y);
        acc = __fadd_rn(acc, v[q].z);
        acc = __fadd_rn(acc, v[q].w);
      }
    }
    float mu = __fdiv_rn(acc, 8192.0f);
    float vacc = 0.0f;
    for (int r = 0; r < 8192; r += 32) {
      float4 v[8];
#pragma unroll
      for (int q = 0; q < 8; ++q) v[q] = *(const float4*)&buf[r + q * 4];
#pragma unroll
      for (int q = 0; q < 8; ++q) {
        float d0 = __fsub_rn(v[q].x, mu); vacc = __fadd_rn(vacc, __fmul_rn(d0, d0));
        float d1 = __fsub_rn(v[q].y, mu); vacc = __fadd_rn(vacc, __fmul_rn(d1, d1));
        float d2 = __fsub_rn(v[q].z, mu); vacc = __fadd_rn(vacc, __fmul_rn(d2, d2));
        float d3 = __fsub_rn(v[q].w, mu); vacc = __fadd_rn(vacc, __fmul_rn(d3, d3));
      }
    }
    float var = __fdiv_rn(vacc, 8192.0f);
    mu32[c] = mu;
    rs32[c] = __fdiv_rn(1.0f, sqrtf(__fadd_rn(var, 1e-5f)));
  }
}

// ---------- 3) fused bn + Hx + row-normalize + bf16 hi/lo split, 8 rows/block ----------
// All per-element / per-output op orders bitwise-identical to the previously
// passing k_bn32 / k_hx / k_norm32 chain.
__global__ __launch_bounds__(256) void k_hxn(const void* __restrict__ H,
    const int* __restrict__ pflag, const float* __restrict__ mu32, const float* __restrict__ rs32,
    const void* __restrict__ gamma, const void* __restrict__ beta,
    const void* __restrict__ Wt, const void* __restrict__ bt,
    float* __restrict__ Hn, float* __restrict__ F1,
    ushort_t* __restrict__ F1hi, ushort_t* __restrict__ F1lo) {
  int flag = *pflag;
  __shared__ float sHn[8][256];
  __shared__ float sHx[8][256];
  __shared__ float sp[8][16];
  __shared__ float snrm[8];
  const int r0 = blockIdx.x * 8;
  const int n = threadIdx.x;
  float g  = ldin(gamma, flag, n);
  float b  = ldin(beta, flag, n);
  float mu = mu32[n], rs = rs32[n];
#pragma unroll
  for (int r = 0; r < 8; ++r) {
    float t = __fsub_rn(ldin(H, flag, (size_t)(r0 + r) * DD + n), mu);
    t = __fmul_rn(t, rs);
    t = __fmul_rn(t, g);
    t = __fadd_rn(t, b);
    sHn[r][n] = t;
    Hn[(size_t)(r0 + r) * DD + n] = t;
  }
  __syncthreads();
  float acc[8];
#pragma unroll
  for (int r = 0; r < 8; ++r) acc[r] = 0.0f;
#pragma unroll 8
  for (int k = 0; k < DD; ++k) {
    float w = ldin(Wt, flag, (size_t)k * DD + n);
#pragma unroll
    for (int r = 0; r < 8; ++r) acc[r] = fmaf(sHn[r][k], w, acc[r]);
  }
  float btn = ldin(bt, flag, n);
#pragma unroll
  for (int r = 0; r < 8; ++r) sHx[r][n] = __fadd_rn(acc[r], btn);
  __syncthreads();
  if (n < 128) {
    int r = n >> 4, s = n & 15;
    int base = (s >> 3) * 128 + (s & 7);
    float e0 = sHx[r][base];
    float part = __fmul_rn(e0, e0);
#pragma unroll
    for (int t = 1; t < 16; ++t) {
      float e = sHx[r][base + 8 * t];
      part = __fadd_rn(part, __fmul_rn(e, e));
    }
    sp[r][s] = part;
  }
  __syncthreads();
  if (n < 8) {
    const float* p = sp[n];
    float P1 = __fadd_rn(__fadd_rn(__fadd_rn(p[0], p[1]), __fadd_rn(p[2], p[3])),
                         __fadd_rn(__fadd_rn(p[4], p[5]), __fadd_rn(p[6], p[7])));
    float P2 = __fadd_rn(__fadd_rn(__fadd_rn(p[8], p[9]), __fadd_rn(p[10], p[11])),
                         __fadd_rn(__fadd_rn(p[12], p[13]), __fadd_rn(p[14], p[15])));
    snrm[n] = fmaxf(sqrtf(__fadd_rn(P1, P2)), 1e-12f);
  }
  __syncthreads();
#pragma unroll
  for (int r = 0; r < 8; ++r) {
    float xn = __fdiv_rn(sHx[r][n], snrm[r]);
    size_t idx = (size_t)(r0 + r) * DD + n;
    F1[idx] = xn;
    bf16 hi = __float2bfloat16(xn);
    float lo = __fsub_rn(xn, __bfloat162float(hi));
    F1hi[idx] = *(ushort_t*)&hi;
    bf16 lob = __float2bfloat16(lo);
    F1lo[idx] = *(ushort_t*)&lob;
  }
}

// ---------- 4) S-chunk GEMM via global_load_lds: S = hh + hl + lh ----------
__global__ __launch_bounds__(256) void k_gemm_s(
    const ushort_t* __restrict__ F1hi, const ushort_t* __restrict__ F1lo,
    int jc, float* __restrict__ S) {
  __shared__ __align__(16) ushort_t AH[4096];
  __shared__ __align__(16) ushort_t AL[4096];
  __shared__ __align__(16) ushort_t BH[4096];
  __shared__ __align__(16) ushort_t BL[4096];
  const int tid = threadIdx.x;
  const int w = tid >> 6, lane = tid & 63;
  const int quad = lane >> 4, l15 = lane & 15;
  const int wi = w >> 1, wj = w & 1;
  const int i0 = blockIdx.y * 128;
  const int j0loc = blockIdx.x * 128;
  const int j0 = jc * 2048 + j0loc;

  const int rofs = lane >> 2;
  const int ccl  = (lane & 3) ^ (rofs & 3);
  const int laneElem = rofs * DD + ccl * 8;

  f32x4 acc[4][4];
#pragma unroll
  for (int fr = 0; fr < 4; ++fr)
#pragma unroll
    for (int fc = 0; fc < 4; ++fc) acc[fr][fc] = (f32x4)0.0f;

  for (int chunk = 0; chunk < 8; ++chunk) {
    const int kofs = chunk * 32;
    __syncthreads();
#pragma unroll
    for (int q = 0; q < 2; ++q) {
      const int s = w * 2 + q;
      const size_t ga = (size_t)(i0 + s * 16) * DD + kofs;
      const size_t gb = (size_t)(j0 + s * 16) * DD + kofs;
      GL2LDS(F1hi + ga + laneElem, &AH[s * 512]);
      GL2LDS(F1lo + ga + laneElem, &AL[s * 512]);
      GL2LDS(F1hi + gb + laneElem, &BH[s * 512]);
      GL2LDS(F1lo + gb + laneElem, &BL[s * 512]);
    }
    __syncthreads();
    short8 ah[4], al[4], bh[4], bl[4];
#pragma unroll
    for (int fr = 0; fr < 4; ++fr) {
      int row = wi * 64 + fr * 16 + l15;
      int g = quad ^ (row & 3);
      ah[fr] = *(const short8*)&AH[row * 32 + g * 8];
      al[fr] = *(const short8*)&AL[row * 32 + g * 8];
    }
#pragma unroll
    for (int fc = 0; fc < 4; ++fc) {
      int row = wj * 64 + fc * 16 + l15;
      int g = quad ^ (row & 3);
      bh[fc] = *(const short8*)&BH[row * 32 + g * 8];
      bl[fc] = *(const short8*)&BL[row * 32 + g * 8];
    }
#pragma unroll
    for (int fr = 0; fr < 4; ++fr)
#pragma unroll
      for (int fc = 0; fc < 4; ++fc) {
        acc[fr][fc] = __builtin_amdgcn_mfma_f32_16x16x32_bf16(ah[fr], bh[fc], acc[fr][fc], 0, 0, 0);
        acc[fr][fc] = __builtin_amdgcn_mfma_f32_16x16x32_bf16(ah[fr], bl[fc], acc[fr][fc], 0, 0, 0);
        acc[fr][fc] = __builtin_amdgcn_mfma_f32_16x16x32_bf16(al[fr], bh[fc], acc[fr][fc], 0, 0, 0);
      }
  }
#pragma unroll
  for (int fr = 0; fr < 4; ++fr) {
#pragma unroll
    for (int reg = 0; reg < 4; ++reg) {
      int row = i0 + wi * 64 + fr * 16 + quad * 4 + reg;
#pragma unroll
      for (int fc = 0; fc < 4; ++fc) {
        int coll = j0loc + wj * 64 + fc * 16 + l15;
        S[(size_t)row * 2048 + coll] = acc[fr][fc][reg];
      }
    }
  }
}

// ---------- 5) per-chunk top-8 scan of S; guarded ins8 + bitonic merge ----------
__global__ __launch_bounds__(256) void k_scan(const float* __restrict__ S, int jc,
                                              float* __restrict__ candv, int* __restrict__ candi) {
  int w = threadIdx.x >> 6, lane = threadIdx.x & 63;
  int row = blockIdx.x * 4 + w;
  const int jbase = jc * 2048;
  float lv[8]; int li[8];
#pragma unroll
  for (int e = 0; e < 8; ++e) { lv[e] = -3.0e38f; li[e] = 0x7fffffff; }
  const float* p = S + (size_t)row * 2048;
#pragma unroll
  for (int it = 0; it < 8; ++it) {
    int col = it * 256 + lane * 4;
    float4 v = *(const float4*)&p[col];
    float m4 = fmaxf(fmaxf(v.x, v.y), fmaxf(v.z, v.w));
    if (m4 > lv[7]) {   // exact-equivalent skip: all 4 would early-return otherwise
      ins8(v.x, jbase + col + 0, lv, li);
      ins8(v.y, jbase + col + 1, lv, li);
      ins8(v.z, jbase + col + 2, lv, li);
      ins8(v.w, jbase + col + 3, lv, li);
    }
  }
#pragma unroll
  for (int m = 1; m <= 32; m <<= 1) {
    float bv[8]; int bi[8];
#pragma unroll
    for (int e = 0; e < 8; ++e) {
      bv[e] = __shfl_xor(lv[e], m, 64);
      bi[e] = __shfl_xor(li[e], m, 64);
    }
#pragma unroll
    for (int e = 0; e < 8; ++e) {
      bool t = lexgt(lv[e], li[e], bv[7 - e], bi[7 - e]);
      lv[e] = t ? lv[e] : bv[7 - e];
      li[e] = t ? li[e] : bi[7 - e];
    }
#pragma unroll
    for (int d = 4; d >= 1; d >>= 1) {
#pragma unroll
      for (int e = 0; e < 8; ++e) {
        if ((e & d) == 0) {
          int f = e + d;
          bool sw = lexgt(lv[f], li[f], lv[e], li[e]);
          float tv = lv[e]; int ti = li[e];
          lv[e] = sw ? lv[f] : lv[e];  li[e] = sw ? li[f] : li[e];
          lv[f] = sw ? tv : lv[f];     li[f] = sw ? ti : li[f];
        }
      }
    }
  }
  if (lane == 0) {
    size_t base = ((size_t)row * 4 + jc) * 8;
#pragma unroll
    for (int e = 0; e < 8; ++e) { candv[base + e] = lv[e]; candi[base + e] = li[e]; }
  }
}

// ---------- 6) merge 4 per-chunk lists -> global top-8 per row ----------
__global__ void k_merge(const float* __restrict__ candv, const int* __restrict__ candi,
                        int* __restrict__ cand8) {
  int row = blockIdx.x * 256 + threadIdx.x;
  float bv[8]; int bj[8];
#pragma unroll
  for (int e = 0; e < 8; ++e) { bv[e] = -3.0e38f; bj[e] = 0x7fffffff; }
  for (int t = 0; t < 32; ++t) {
    float v = candv[(size_t)row * 32 + t];
    int j   = candi[(size_t)row * 32 + t];
    ins8t(v, j, bv, bj);
  }
#pragma unroll
  for (int e = 0; e < 8; ++e) cand8[row * 8 + e] = bj[e];
}

// ---------- 7) re-rank candidates with bitwise fp32-numpy mimic chain ----------
__global__ void k_rerank(const float* __restrict__ F1, const int* __restrict__ cand8,
                         int* __restrict__ top5i, float* __restrict__ top5v,
                         float* __restrict__ dinv) {
  int w = threadIdx.x >> 6, lane = threadIdx.x & 63;
  int row = blockIdx.x * 4 + w;
  int jl = 0x7fffffff;
  float a32 = -1.0f;
  if (lane < 8) {
    jl = cand8[row * 8 + lane];
    const float* xi = F1 + (size_t)row * DD;
    const float* xj = F1 + (size_t)jl * DD;
    float acc = 0.0f;
#pragma unroll 8
    for (int k = 0; k < DD; ++k)
      acc = fmaf(xi[k], xj[k], acc);
    float d = fminf(fmaxf(acc, -1.0f), 1.0f);
    float sam = acosf(d);
    float xx = expf(__fmul_rn(-0.2f, sam));
    float sig = __fdiv_rn(1.0f, __fadd_rn(1.0f, expf(-xx)));
    a32 = fmaxf(sig, 0.1f);
  }
  float av[8]; int aj[8];
#pragma unroll
  for (int l = 0; l < 8; ++l) { av[l] = __shfl(a32, l, 64); aj[l] = __shfl(jl, l, 64); }
  if (lane == 0) {
    bool used[8] = {false,false,false,false,false,false,false,false};
    double dsum = 0.0;
#pragma unroll
    for (int k = 0; k < 5; ++k) {
      float bv = -2.0f; int bj = 0x7fffffff; int bs = -1;
#pragma unroll
      for (int s = 0; s < 8; ++s) {
        bool better = (!used[s]) && ((av[s] > bv) || (av[s] == bv && aj[s] < bj));
        bs = better ? s : bs;
        bv = better ? av[s] : bv;
        bj = better ? aj[s] : bj;
      }
#pragma unroll
      for (int s = 0; s < 8; ++s) used[s] = used[s] || (s == bs);
      top5i[row * 5 + k] = bj;
      top5v[row * 5 + k] = bv;
      dsum += (double)bv;
    }
    dinv[row] = (float)(1.0 / sqrt(dsum));
  }
}

// ---------- 8) fused Z = A_hat@Hn and out = LeakyReLU(Z@W_out + srow*b_out) ----------
__global__ __launch_bounds__(256) void k_zout(const float* __restrict__ Hn,
    const int* __restrict__ top5i, const float* __restrict__ top5v,
    const float* __restrict__ dinv, const void* __restrict__ Wo,
    const void* __restrict__ bo, const int* __restrict__ pflag, void* __restrict__ outp) {
  int flag = *pflag;
  __shared__ float sZ[8][256];
  __shared__ float ssr[8];
  const int r0 = blockIdx.x * 8;
  const int n = threadIdx.x;
#pragma unroll
  for (int r = 0; r < 8; ++r) {
    int i = r0 + r;
    float di = dinv[i];
    double z = 0.0;
    float sr = 0.0f;
#pragma unroll
    for (int k = 0; k < 5; ++k) {
      int j = top5i[i * 5 + k];
      float wgt = di * top5v[i * 5 + k] * dinv[j];
      z += (double)wgt * (double)Hn[(size_t)j * DD + n];
      sr += wgt;
    }
    sZ[r][n] = (float)z;
    if (n == 0) ssr[r] = sr;
  }
  __syncthreads();
  float acc[8];
#pragma unroll
  for (int r = 0; r < 8; ++r) acc[r] = 0.0f;
#pragma unroll 8
  for (int k = 0; k < DD; ++k) {
    float w = ldin(Wo, flag, (size_t)k * DD + n);
#pragma unroll
    for (int r = 0; r < 8; ++r) acc[r] = fmaf(sZ[r][k], w, acc[r]);
  }
  float bon = ldin(bo, flag, n);
#pragma unroll
  for (int r = 0; r < 8; ++r) {
    float v = acc[r] + ssr[r] * bon;
    v = (v >= 0.0f) ? v : 0.01f * v;
    size_t idx = (size_t)(r0 + r) * DD + n;
    if (flag) ((bf16*)outp)[idx] = __float2bfloat16(v);
    else      ((float*)outp)[idx] = v;
  }
}

// ---------- 9) fused zero + scatter: block owns 2 rows of A ----------
__global__ __launch_bounds__(256) void k_zeroscatter(void* __restrict__ d_out,
    const int* __restrict__ pflag, const int* __restrict__ top5i,
    const float* __restrict__ top5v) {
  int flag = *pflag;
  size_t esize = flag ? 2 : 4;
  int r0 = blockIdx.x * 2;
  char* Abase = (char*)d_out + (size_t)NN * DD * esize;
  uint4* rowp = (uint4*)(Abase + (size_t)r0 * NN * esize);
  int nvec = (int)((2 * (size_t)NN * esize) >> 4);
  uint4 z; z.x = 0; z.y = 0; z.z = 0; z.w = 0;
  for (int i = threadIdx.x; i < nvec; i += 256) rowp[i] = z;
  __syncthreads();
  int t = threadIdx.x;
  if (t < 10) {
    int r = r0 + t / 5, k = t % 5;
    int col = top5i[r * 5 + k];
    float v = top5v[r * 5 + k];
    if (flag) ((bf16*)Abase)[(size_t)r * NN + col] = __float2bfloat16(v);
    else      ((float*)Abase)[(size_t)r * NN + col] = v;
  }
}

extern "C" void kernel_launch(void* const* d_in, const int* in_sizes, int n_in,
                              void* d_out, int out_size, void* d_ws, size_t ws_size,
                              hipStream_t stream) {
  (void)in_sizes; (void)n_in; (void)out_size; (void)ws_size;
  const void* H     = d_in[0];
  const void* gamma = d_in[1];
  const void* beta  = d_in[2];
  const void* Wt    = d_in[3];
  const void* bt    = d_in[4];
  const void* Wo    = d_in[5];
  const void* bo    = d_in[6];

  // scratch zone inside the A-output region (valid in both dtype worlds), freed by k_zeroscatter
  const size_t MB = 1048576;
  char* zb = (char*)d_out + 8 * MB;
  float*    Hn32  = (float*)(zb + 0);              // 8 MiB
  float*    F1_32 = (float*)(zb + 8 * MB);         // 8 MiB
  ushort_t* F1hi  = (ushort_t*)(zb + 16 * MB);     // 4 MiB
  ushort_t* F1lo  = (ushort_t*)(zb + 20 * MB);     // 4 MiB
  float*    candv = (float*)(zb + 24 * MB);        // 1 MiB
  int*      candi = (int*)(zb + 25 * MB);          // 1 MiB
  float*    HT    = (float*)(zb + 36 * MB);        // 8 MiB [DD][NN]
  float*    mu32  = (float*)(zb + 44 * MB);        // 1 KiB
  float*    rs32  = (float*)(zb + 44 * MB + 4096); // 1 KiB
  int*      cand8 = (int*)(zb + 44 * MB + 8192);   // 256 KiB
  float*    dinv  = (float*)(zb + 44 * MB + 270336);  // 32 KiB
  float*    Schunk= (float*)(zb + 48 * MB);        // 64 MiB [8192][2048]

  // d_ws: only what must survive into k_zeroscatter
  char* ws = (char*)d_ws;
  int*   flag  = (int*)(ws + 0);
  int*   top5i = (int*)(ws + 256);       // 160 KiB
  float* top5v = (float*)(ws + 164096);  // 160 KiB

  k_detect<<<dim3(1), dim3(256), 0, stream>>>((const ushort_t*)H, flag);
  k_transposeH<<<dim3(128, 4), dim3(256), 0, stream>>>(H, flag, HT);
  k_statsT<<<dim3(256), dim3(256), 0, stream>>>(HT, mu32, rs32);
  k_hxn<<<dim3(1024), dim3(256), 0, stream>>>(H, flag, mu32, rs32, gamma, beta,
                                              Wt, bt, Hn32, F1_32, F1hi, F1lo);
  for (int jc = 0; jc < 4; ++jc) {
    k_gemm_s<<<dim3(16, 64), dim3(256), 0, stream>>>(F1hi, F1lo, jc, Schunk);
    k_scan<<<dim3(2048), dim3(256), 0, stream>>>(Schunk, jc, candv, candi);
  }
  k_merge<<<dim3(32), dim3(256), 0, stream>>>(candv, candi, cand8);
  k_rerank<<<dim3(2048), dim3(256), 0, stream>>>(F1_32, cand8, top5i, top5v, dinv);
  k_zout<<<dim3(1024), dim3(256), 0, stream>>>(Hn32, top5i, top5v, dinv, Wo, bo, flag, d_out);
  k_zeroscatter<<<dim3(4096), dim3(256), 0, stream>>>(d_out, flag, top5i, top5v);
}